// Round 2
// baseline (4896.737 us; speedup 1.0000x reference)
//
#include <hip/hip_runtime.h>
#include <hip/hip_bf16.h>
#include <math.h>
#include <type_traits>

// B=8, L=1024, D=1024, H=16, HD=64, K=7, DI=2048, DS=16, DC=4, DTR=64

// ---------------------------------------------------------------------------
// Generic f32 GEMM: C[M,N] = act(A[M,K] @ B[K,N] + bias[N]); CT = f32 or bf16
// Tile 128x128, BK=8, 256 threads, 8x8 per thread. M%128==0, K%8==0 assumed.
// ACT: 0 = none, 1 = softplus
// ---------------------------------------------------------------------------
template <int ACT, typename CT>
__global__ __launch_bounds__(256) void gemm_f32(
    const float* __restrict__ A, int lda,
    const float* __restrict__ B, int ldb,
    CT* __restrict__ C, int ldc,
    int M, int N, int Kd,
    const float* __restrict__ bias)
{
    __shared__ float As[8][128];
    __shared__ float Bs[8][128];

    const int bm = blockIdx.y * 128;
    const int bn = blockIdx.x * 128;
    const int t = threadIdx.x;
    const int tx = t & 15;
    const int ty = t >> 4;

    const int arow = t >> 1;
    const int akk = (t & 1) * 4;
    const int bkk = t >> 5;
    const int bcol = (t & 31) * 4;

    float acc[8][8];
#pragma unroll
    for (int i = 0; i < 8; ++i)
#pragma unroll
        for (int j = 0; j < 8; ++j) acc[i][j] = 0.f;

    for (int k0 = 0; k0 < Kd; k0 += 8) {
        const float4 av = *reinterpret_cast<const float4*>(
            A + (size_t)(bm + arow) * lda + k0 + akk);
        As[akk + 0][arow] = av.x;
        As[akk + 1][arow] = av.y;
        As[akk + 2][arow] = av.z;
        As[akk + 3][arow] = av.w;
        float4 bv = make_float4(0.f, 0.f, 0.f, 0.f);
        if (bn + bcol < N) {
            bv = *reinterpret_cast<const float4*>(
                B + (size_t)(k0 + bkk) * ldb + bn + bcol);
        }
        *reinterpret_cast<float4*>(&Bs[bkk][bcol]) = bv;
        __syncthreads();

#pragma unroll
        for (int kk = 0; kk < 8; ++kk) {
            const float4 a0 = *reinterpret_cast<const float4*>(&As[kk][ty * 8]);
            const float4 a1 = *reinterpret_cast<const float4*>(&As[kk][ty * 8 + 4]);
            const float4 b0 = *reinterpret_cast<const float4*>(&Bs[kk][tx * 8]);
            const float4 b1 = *reinterpret_cast<const float4*>(&Bs[kk][tx * 8 + 4]);
            const float a[8] = {a0.x, a0.y, a0.z, a0.w, a1.x, a1.y, a1.z, a1.w};
            const float b[8] = {b0.x, b0.y, b0.z, b0.w, b1.x, b1.y, b1.z, b1.w};
#pragma unroll
            for (int i = 0; i < 8; ++i)
#pragma unroll
                for (int j = 0; j < 8; ++j) acc[i][j] += a[i] * b[j];
        }
        __syncthreads();
    }

#pragma unroll
    for (int i = 0; i < 8; ++i) {
        const int row = bm + ty * 8 + i;
        CT* cp = C + (size_t)row * ldc + bn + tx * 8;
#pragma unroll
        for (int j = 0; j < 8; ++j) {
            const int col = bn + tx * 8 + j;
            if (col < N) {
                float v = acc[i][j];
                if (bias) v += bias[col];
                if (ACT == 1) v = (v > 20.f) ? v : log1pf(__expf(v));
                if constexpr (std::is_same<CT, __hip_bfloat16>::value)
                    cp[j] = __float2bfloat16(v);
                else
                    cp[j] = v;
            }
        }
    }
}

// ---------------------------------------------------------------------------
// Attention: one thread per q-row, online softmax, KV tiles staged in LDS.
// ---------------------------------------------------------------------------
__global__ __launch_bounds__(256) void attn_kernel(
    const float* __restrict__ full, const int* __restrict__ mask,
    float* __restrict__ out)
{
    __shared__ float Ks[64][64];
    __shared__ float Vs[64][64];
    __shared__ float Msk[64];

    const int t = threadIdx.x;
    const int bid = blockIdx.x;
    const int qt = bid & 3;
    const int bh = bid >> 2;
    const int h = bh & 15;
    const int b = bh >> 4;
    const int qrow = qt * 256 + t;

    const float* qp = full + ((size_t)(b * 1024 + qrow)) * 4096 + h * 64;
    float q[64];
#pragma unroll
    for (int d = 0; d < 64; d += 4) {
        const float4 v4 = *reinterpret_cast<const float4*>(qp + d);
        q[d] = v4.x; q[d + 1] = v4.y; q[d + 2] = v4.z; q[d + 3] = v4.w;
    }

    float acc[64];
#pragma unroll
    for (int d = 0; d < 64; ++d) acc[d] = 0.f;
    float m = 0.f;   // valid lower bound of row max (diag score >= 0)
    float lsum = 0.f;

    for (int kt = 0; kt < 16; ++kt) {
        __syncthreads();
        {
            const int r = t >> 2;
            const int c0 = (t & 3) * 16;
            const float* kp = full + ((size_t)(b * 1024 + kt * 64 + r)) * 4096 + 1024 + h * 64 + c0;
            const float* vp = kp + 1024;
#pragma unroll
            for (int c = 0; c < 16; c += 4) {
                *reinterpret_cast<float4*>(&Ks[r][c0 + c]) = *reinterpret_cast<const float4*>(kp + c);
                *reinterpret_cast<float4*>(&Vs[r][c0 + c]) = *reinterpret_cast<const float4*>(vp + c);
            }
            if (t < 64) Msk[t] = (float)mask[b * 1024 + kt * 64 + t];
        }
        __syncthreads();

        for (int j = 0; j < 64; ++j) {
            float s = 0.f;
            const float4* kr = reinterpret_cast<const float4*>(&Ks[j][0]);
#pragma unroll
            for (int d4 = 0; d4 < 16; ++d4) {
                const float4 kv = kr[d4];
                s += q[d4 * 4 + 0] * kv.x + q[d4 * 4 + 1] * kv.y +
                     q[d4 * 4 + 2] * kv.z + q[d4 * 4 + 3] * kv.w;
            }
            s *= 0.125f;
            const int ka = kt * 64 + j;
            int dd = qrow - ka; if (dd < 0) dd = -dd;
            if (1024 - dd < dd) dd = 1024 - dd;
            s -= (float)dd;
            if (Msk[j] == 0.f) s = -1e9f;

            if (s > m) {
                const float c = __expf(m - s);
                lsum *= c;
#pragma unroll
                for (int d = 0; d < 64; ++d) acc[d] *= c;
                m = s;
            }
            const float p = __expf(s - m);
            lsum += p;
            if (p > 1e-12f) {
                const float4* vr = reinterpret_cast<const float4*>(&Vs[j][0]);
#pragma unroll
                for (int d4 = 0; d4 < 16; ++d4) {
                    const float4 vv = vr[d4];
                    acc[d4 * 4 + 0] += p * vv.x;
                    acc[d4 * 4 + 1] += p * vv.y;
                    acc[d4 * 4 + 2] += p * vv.z;
                    acc[d4 * 4 + 3] += p * vv.w;
                }
            }
        }
    }

    const float inv = 1.f / lsum;
    float* op = out + ((size_t)(b * 1024 + qrow)) * 1024 + h * 64;
#pragma unroll
    for (int d = 0; d < 64; d += 4) {
        float4 o4;
        o4.x = acc[d] * inv; o4.y = acc[d + 1] * inv;
        o4.z = acc[d + 2] * inv; o4.w = acc[d + 3] * inv;
        *reinterpret_cast<float4*>(op + d) = o4;
    }
}

// ---------------------------------------------------------------------------
__global__ __launch_bounds__(256) void rmsnorm_kernel(
    const float* __restrict__ in, const float* __restrict__ w,
    float* __restrict__ out)
{
    const int row = blockIdx.x;
    const int t = threadIdx.x;
    const float* x = in + (size_t)row * 1024;
    const float4 v = *reinterpret_cast<const float4*>(x + t * 4);
    float ss = v.x * v.x + v.y * v.y + v.z * v.z + v.w * v.w;
#pragma unroll
    for (int o = 32; o; o >>= 1) ss += __shfl_down(ss, o, 64);
    __shared__ float wsum[4];
    if ((t & 63) == 0) wsum[t >> 6] = ss;
    __syncthreads();
    const float tot = wsum[0] + wsum[1] + wsum[2] + wsum[3];
    const float scale = rsqrtf(tot * (1.f / 1024.f) + 1e-6f);
    const float4 wv = *reinterpret_cast<const float4*>(w + t * 4);
    float4 o4;
    o4.x = v.x * scale * wv.x; o4.y = v.y * scale * wv.y;
    o4.z = v.z * scale * wv.z; o4.w = v.w * scale * wv.w;
    *reinterpret_cast<float4*>(out + (size_t)row * 1024 + t * 4) = o4;
}

// ---------------------------------------------------------------------------
// Circular depthwise conv K=7. base strided (4096), out [B,L,1024].
// ---------------------------------------------------------------------------
__global__ __launch_bounds__(256) void circconv_kernel(
    const float* __restrict__ base, const float* __restrict__ cw,
    const float* __restrict__ cb, float* __restrict__ out)
{
    const int idx = blockIdx.x * 256 + threadIdx.x;
    const int d = (idx & 255) * 4;
    const int bl = idx >> 8;
    const int l = bl & 1023;
    const int b = bl >> 10;
    float4 acc = make_float4(cb[d], cb[d + 1], cb[d + 2], cb[d + 3]);
#pragma unroll
    for (int k = 0; k < 7; ++k) {
        const int ll = (l + k - 3 + 1024) & 1023;
        const float4 xv = *reinterpret_cast<const float4*>(
            base + ((size_t)(b * 1024 + ll)) * 4096 + d);
        acc.x += xv.x * cw[(d + 0) * 7 + k];
        acc.y += xv.y * cw[(d + 1) * 7 + k];
        acc.z += xv.z * cw[(d + 2) * 7 + k];
        acc.w += xv.w * cw[(d + 3) * 7 + k];
    }
    *reinterpret_cast<float4*>(out + (size_t)bl * 1024 + d) = acc;
}

// ---------------------------------------------------------------------------
// Mamba causal conv DC=4 + SiLU. u at stride 4096 (cols 0..2047 of full),
// uc at stride 4096 (cols 2048..4095).
// ---------------------------------------------------------------------------
__global__ __launch_bounds__(256) void mconv_kernel(
    const float* __restrict__ u, const float* __restrict__ w,
    const float* __restrict__ bconv, float* __restrict__ uc)
{
    const int idx = blockIdx.x * 256 + threadIdx.x;  // B*L*512 float4 groups
    const int d = (idx & 511) * 4;
    const int bl = idx >> 9;
    const int l = bl & 1023;
    float4 acc = make_float4(bconv[d], bconv[d + 1], bconv[d + 2], bconv[d + 3]);
#pragma unroll
    for (int k = 0; k < 4; ++k) {
        const int ll = l + k - 3;
        if (ll >= 0) {
            const float4 xv = *reinterpret_cast<const float4*>(
                u + ((size_t)(bl + ll - l)) * 4096 + d);
            acc.x += xv.x * w[(d + 0) * 4 + k];
            acc.y += xv.y * w[(d + 1) * 4 + k];
            acc.z += xv.z * w[(d + 2) * 4 + k];
            acc.w += xv.w * w[(d + 3) * 4 + k];
        }
    }
    acc.x = acc.x / (1.f + __expf(-acc.x));
    acc.y = acc.y / (1.f + __expf(-acc.y));
    acc.z = acc.z / (1.f + __expf(-acc.z));
    acc.w = acc.w / (1.f + __expf(-acc.w));
    *reinterpret_cast<float4*>(uc + (size_t)bl * 4096 + d) = acc;
}

// ---------------------------------------------------------------------------
// Selective scan. One lane per (b, di, s). dt/uc strided 4096 in `full`;
// yg written in place over dt (wave-lockstep safe). z is bf16 compact.
// ---------------------------------------------------------------------------
__global__ __launch_bounds__(256) void scan_kernel(
    float* __restrict__ dt_yg, const float* __restrict__ uc,
    const float* __restrict__ xdbl, const __hip_bfloat16* __restrict__ zb,
    const float* __restrict__ A_log, const float* __restrict__ Dp)
{
    const int g = blockIdx.x * 256 + threadIdx.x;
    const int s = g & 15;
    const int ch = g >> 4;
    const int di = ch & 2047;
    const int b = ch >> 11;

    const float A = -__expf(A_log[di * 16 + s]);
    const float Dv = Dp[di];
    float h = 0.f;
    const size_t base_di = (size_t)b * 1024 * 4096 + di;
    const size_t base_x = (size_t)b * 1024 * 96;
    const size_t base_z = (size_t)b * 1024 * 2048 + di;

    for (int t = 0; t < 1024; ++t) {
        const float dtv = dt_yg[base_di + (size_t)t * 4096];
        const float uv = uc[base_di + (size_t)t * 4096 + 2048];
        const float Bv = xdbl[base_x + t * 96 + 64 + s];
        const float Cv = xdbl[base_x + t * 96 + 80 + s];
        const float e = __expf(dtv * A);
        h = e * h + dtv * uv * Bv;
        float y = h * Cv;
        y += __shfl_xor(y, 1, 64);
        y += __shfl_xor(y, 2, 64);
        y += __shfl_xor(y, 4, 64);
        y += __shfl_xor(y, 8, 64);
        if (s == 0) {
            const float zv = (float)zb[base_z + (size_t)t * 2048];
            const float yf = y + uv * Dv;
            const float sig = 1.f / (1.f + __expf(-zv));
            dt_yg[base_di + (size_t)t * 4096] = yf * zv * sig;
        }
    }
}

// ---------------------------------------------------------------------------
__global__ __launch_bounds__(256) void means_kernel(
    const float* __restrict__ a, const float* __restrict__ m,
    const float* __restrict__ c, float* __restrict__ ri)
{
    const int idx = blockIdx.x * 256 + threadIdx.x;  // 24576
    const int d = idx & 1023;
    const int br = (idx >> 10) % 3;
    const int b = idx / 3072;
    const float* src = (br == 0) ? a : ((br == 1) ? m : c);
    const float* p = src + (size_t)b * 1024 * 1024 + d;
    float sum = 0.f;
    for (int l = 0; l < 1024; ++l) sum += p[(size_t)l * 1024];
    ri[idx] = sum * (1.f / 1024.f);
}

// ---------------------------------------------------------------------------
__global__ __launch_bounds__(256) void router1_kernel(
    const float* __restrict__ ri, const float* __restrict__ w1,
    const float* __restrict__ b1, float* __restrict__ h1)
{
    __shared__ float rs[3072];
    const int b = blockIdx.y;
    const int jc = blockIdx.x;
    const int t = threadIdx.x;
    for (int i = t; i < 3072; i += 256) rs[i] = ri[b * 3072 + i];
    __syncthreads();
    const int j = jc * 256 + t;
    float acc = b1[j];
    for (int i = 0; i < 3072; ++i) acc += rs[i] * w1[(size_t)i * 1024 + j];
    h1[b * 1024 + j] = 0.5f * acc * (1.f + erff(acc * 0.70710678118654752f));
}

// ---------------------------------------------------------------------------
__global__ __launch_bounds__(256) void router2_kernel(
    const float* __restrict__ h1, const float* __restrict__ w2,
    const float* __restrict__ b2, float* __restrict__ gates)
{
    const int b = blockIdx.x;
    const int t = threadIdx.x;
    float p0 = 0.f, p1 = 0.f, p2 = 0.f;
    for (int j = t; j < 1024; j += 256) {
        const float hv = h1[b * 1024 + j];
        p0 += hv * w2[j * 3 + 0];
        p1 += hv * w2[j * 3 + 1];
        p2 += hv * w2[j * 3 + 2];
    }
#pragma unroll
    for (int o = 32; o; o >>= 1) {
        p0 += __shfl_down(p0, o, 64);
        p1 += __shfl_down(p1, o, 64);
        p2 += __shfl_down(p2, o, 64);
    }
    __shared__ float r0[4], r1[4], r2[4];
    if ((t & 63) == 0) { r0[t >> 6] = p0; r1[t >> 6] = p1; r2[t >> 6] = p2; }
    __syncthreads();
    if (t == 0) {
        float l0 = r0[0] + r0[1] + r0[2] + r0[3] + b2[0];
        float l1 = r1[0] + r1[1] + r1[2] + r1[3] + b2[1];
        float l2 = r2[0] + r2[1] + r2[2] + r2[3] + b2[2];
        const float mx = fmaxf(l0, fmaxf(l1, l2));
        const float e0 = __expf(l0 - mx), e1 = __expf(l1 - mx), e2 = __expf(l2 - mx);
        const float inv = 1.f / (e0 + e1 + e2);
        gates[b * 3 + 0] = e0 * inv;
        gates[b * 3 + 1] = e1 * inv;
        gates[b * 3 + 2] = e2 * inv;
    }
}

// ---------------------------------------------------------------------------
__global__ __launch_bounds__(256) void fuse_kernel(
    float* __restrict__ a, const float* __restrict__ m,
    const float* __restrict__ c, const float* __restrict__ gates)
{
    const int idx = blockIdx.x * 256 + threadIdx.x;
    const int b = idx >> 18;
    const float g0 = gates[b * 3 + 0];
    const float g1 = gates[b * 3 + 1];
    const float g2 = gates[b * 3 + 2];
    const float4 av = reinterpret_cast<const float4*>(a)[idx];
    const float4 mv = reinterpret_cast<const float4*>(m)[idx];
    const float4 cv = reinterpret_cast<const float4*>(c)[idx];
    float4 o4;
    o4.x = g0 * av.x + g1 * mv.x + g2 * cv.x;
    o4.y = g0 * av.y + g1 * mv.y + g2 * cv.y;
    o4.z = g0 * av.z + g1 * mv.z + g2 * cv.z;
    o4.w = g0 * av.w + g1 * mv.w + g2 * cv.w;
    reinterpret_cast<float4*>(a)[idx] = o4;
}

// ---------------------------------------------------------------------------
extern "C" void kernel_launch(void* const* d_in, const int* in_sizes, int n_in,
                              void* d_out, int out_size, void* d_ws, size_t ws_size,
                              hipStream_t stream)
{
    const float* x        = (const float*)d_in[0];
    const int*   mask     = (const int*)d_in[1];
    const float* W_in     = (const float*)d_in[2];
    const float* b_in     = (const float*)d_in[3];
    const float* nw_attn  = (const float*)d_in[4];
    const float* nw_mamba = (const float*)d_in[5];
    const float* nw_cnn   = (const float*)d_in[6];
    const float* conv_w   = (const float*)d_in[7];
    const float* conv_b   = (const float*)d_in[8];
    const float* m_in_w   = (const float*)d_in[9];
    const float* m_conv_w = (const float*)d_in[10];
    const float* m_conv_b = (const float*)d_in[11];
    const float* m_x_w    = (const float*)d_in[12];
    const float* m_dt_w   = (const float*)d_in[13];
    const float* m_dt_b   = (const float*)d_in[14];
    const float* m_A_log  = (const float*)d_in[15];
    const float* m_D      = (const float*)d_in[16];
    const float* m_out_w  = (const float*)d_in[17];
    const float* r_w1     = (const float*)d_in[18];
    const float* r_b1     = (const float*)d_in[19];
    const float* r_w2     = (const float*)d_in[20];
    const float* r_b2     = (const float*)d_in[21];
    const float* W_out    = (const float*)d_in[22];
    const float* b_out    = (const float*)d_in[23];
    float* out = (float*)d_out;
    float* ws = (float*)d_ws;

    // Workspace layout (float slots), total ~51.2M floats = ~195 MiB:
    //   full   [8192,4096] @ 0                      (128 MiB)
    //     after attn: cols 0..2047 = u, later dt, later yg (in place)
    //     after in-proj/cnn: cols 2048..4095 = uc
    //   zreg   @ 33,554,432: bf16 z [8192,2048] (32 MiB); reused as f32
    //          mamba_n [8192,1024] after scan
    //   attn_n @ 41,943,040: [8192,1024] (32 MiB)
    //   xdbl   @ 50,331,648: [8192,96]
    //   ri     @ 51,118,080: [8,3072]; gates @ +24576; h1 @ +24608
    //   cnn_n lives in d_out (dead before final GEMM writes it)
    float* full   = ws;
    __hip_bfloat16* z_bf = (__hip_bfloat16*)(ws + 33554432ull);
    float* mamba_n = ws + 33554432ull;
    float* attn_n  = ws + 41943040ull;
    float* xdbl    = ws + 50331648ull;
    float* ri      = ws + 51118080ull;
    float* gates   = ri + 24576;
    float* h1buf   = gates + 32;
    float* cnn_n   = out;

    const dim3 blk(256);

    // 1. full = x @ W_in + b_in   -> q|k|v|base
    gemm_f32<0, float><<<dim3(32, 64), blk, 0, stream>>>(
        x, 1024, W_in, 4096, full, 4096, 8192, 4096, 1024, b_in);
    // 2. attention branch (consumes q,k,v)
    attn_kernel<<<512, blk, 0, stream>>>(full, mask, attn_n);
    rmsnorm_kernel<<<8192, blk, 0, stream>>>(attn_n, nw_attn, attn_n);
    // 3. cnn branch (reads base) -> d_out
    circconv_kernel<<<8192, blk, 0, stream>>>(full + 3072, conv_w, conv_b, cnn_n);
    rmsnorm_kernel<<<8192, blk, 0, stream>>>(cnn_n, nw_cnn, cnn_n);
    // 4. mamba in-proj: u -> full cols 0..2047 (q,k free now); z -> bf16 buffer
    gemm_f32<0, float><<<dim3(16, 64), blk, 0, stream>>>(
        full + 3072, 4096, m_in_w, 4096, full, 4096, 8192, 2048, 1024, nullptr);
    gemm_f32<0, __hip_bfloat16><<<dim3(16, 64), blk, 0, stream>>>(
        full + 3072, 4096, m_in_w + 2048, 4096, z_bf, 2048, 8192, 2048, 1024, nullptr);
    // 5. causal conv + silu: u (cols 0..2047) -> uc (cols 2048..4095; v,base dead)
    mconv_kernel<<<16384, blk, 0, stream>>>(full, m_conv_w, m_conv_b, full + 2048);
    // 6. x_dbl = uc @ m_x_w (N=96)
    gemm_f32<0, float><<<dim3(1, 64), blk, 0, stream>>>(
        full + 2048, 4096, m_x_w, 96, xdbl, 96, 8192, 96, 2048, nullptr);
    // 7. dt = softplus(x_dbl[:,:64] @ m_dt_w + m_dt_b) -> full cols 0..2047 (u dead)
    gemm_f32<1, float><<<dim3(16, 64), blk, 0, stream>>>(
        xdbl, 96, m_dt_w, 2048, full, 4096, 8192, 2048, 64, m_dt_b);
    // 8. selective scan + skip + silu(z) gating -> yg in place over dt
    scan_kernel<<<1024, blk, 0, stream>>>(full, full, xdbl, z_bf, m_A_log, m_D);
    // 9. mamba out-proj (z region now dead -> mamba_n) + norm
    gemm_f32<0, float><<<dim3(8, 64), blk, 0, stream>>>(
        full, 4096, m_out_w, 1024, mamba_n, 1024, 8192, 1024, 2048, nullptr);
    rmsnorm_kernel<<<8192, blk, 0, stream>>>(mamba_n, nw_mamba, mamba_n);
    // 10. router
    means_kernel<<<96, blk, 0, stream>>>(attn_n, mamba_n, cnn_n, ri);
    router1_kernel<<<dim3(4, 8), blk, 0, stream>>>(ri, r_w1, r_b1, h1buf);
    router2_kernel<<<8, blk, 0, stream>>>(h1buf, r_w2, r_b2, gates);
    // 11. fuse (in place into attn_n) + final GEMM
    fuse_kernel<<<8192, blk, 0, stream>>>(attn_n, mamba_n, cnn_n, gates);
    gemm_f32<0, float><<<dim3(8, 64), blk, 0, stream>>>(
        attn_n, 1024, W_out, 1024, out, 1024, 8192, 1024, 1024, b_out);
}

// Round 3
// 1932.049 us; speedup vs baseline: 2.5345x; 2.5345x over previous
//
#include <hip/hip_runtime.h>
#include <math.h>

// B=8, L=1024, D=1024, H=16, HD=64, K=7, DI=2048, DS=16, DC=4, DTR=64

typedef __bf16 bf16x8 __attribute__((ext_vector_type(8)));
typedef float f32x4 __attribute__((ext_vector_type(4)));

__device__ __forceinline__ float b2f(ushort u) {
    return __uint_as_float(((unsigned int)u) << 16);
}
__device__ __forceinline__ ushort f2b(float f) {
    unsigned int x = __float_as_uint(f);
    return (ushort)((x + 0x7FFFu + ((x >> 16) & 1u)) >> 16);
}
__device__ __forceinline__ void unpack2(unsigned int u, float& a, float& b) {
    a = __uint_as_float(u << 16);
    b = __uint_as_float(u & 0xFFFF0000u);
}
__device__ __forceinline__ void async16(const ushort* g, ushort* l) {
    __builtin_amdgcn_global_load_lds(
        (const __attribute__((address_space(1))) unsigned int*)g,
        (__attribute__((address_space(3))) unsigned int*)l, 16, 0, 0);
}

// ---------------------------------------------------------------------------
// bf16 MFMA GEMM: C[M,N] = act(A[M,K] @ Bt[N,K]^T + bias[N])
// A,Bt bf16 (ushort). Tile 128x128, BK=64, 256 thr (4 waves, 2x2), 4x4 frags.
// M%128==0, N%128==0, K%64==0. Nlim guards C columns (xdbl: N=128,Nlim=96).
// ACT: 0=none, 1=softplus. CT: float or ushort(bf16).
// ---------------------------------------------------------------------------
template <int ACT, typename CT>
__global__ __launch_bounds__(256) void gemm_mfma(
    const ushort* __restrict__ A, int lda,
    const ushort* __restrict__ Bt, int ldb,
    CT* __restrict__ C, int ldc,
    int M, int N, int Kd, int Nlim,
    const float* __restrict__ bias)
{
    __shared__ ushort As[128 * 64];
    __shared__ ushort Bs[128 * 64];

    const int t = threadIdx.x;
    const int wid = t >> 6;
    const int lane = t & 63;
    const int bm = blockIdx.y * 128;
    const int bn = blockIdx.x * 128;
    const int wm = wid >> 1;       // 0..1
    const int wn = wid & 1;        // 0..1
    const int lr = lane & 15;
    const int lk = (lane >> 4) * 8;

    f32x4 acc[4][4];
#pragma unroll
    for (int m = 0; m < 4; ++m)
#pragma unroll
        for (int n = 0; n < 4; ++n) acc[m][n] = (f32x4){0.f, 0.f, 0.f, 0.f};

    for (int k0 = 0; k0 < Kd; k0 += 64) {
        // stage A and Bt tiles: each wave does 4 x 1KB issues per tile
#pragma unroll
        for (int j = 0; j < 4; ++j) {
            const int r0 = wid * 32 + j * 8;
            const int grow = r0 + (lane >> 3);
            const int gcol = (lane & 7) * 8;
            async16(A + (size_t)(bm + grow) * lda + k0 + gcol, &As[r0 * 64]);
            async16(Bt + (size_t)(bn + grow) * ldb + k0 + gcol, &Bs[r0 * 64]);
        }
        __syncthreads();   // compiler drains vmcnt before barrier

#pragma unroll
        for (int kk = 0; kk < 64; kk += 32) {
            bf16x8 af[4], bq[4];
#pragma unroll
            for (int m = 0; m < 4; ++m)
                af[m] = *reinterpret_cast<const bf16x8*>(
                    &As[(wm * 64 + m * 16 + lr) * 64 + kk + lk]);
#pragma unroll
            for (int n = 0; n < 4; ++n)
                bq[n] = *reinterpret_cast<const bf16x8*>(
                    &Bs[(wn * 64 + n * 16 + lr) * 64 + kk + lk]);
#pragma unroll
            for (int m = 0; m < 4; ++m)
#pragma unroll
                for (int n = 0; n < 4; ++n)
                    acc[m][n] = __builtin_amdgcn_mfma_f32_16x16x32_bf16(
                        af[m], bq[n], acc[m][n], 0, 0, 0);
        }
        __syncthreads();
    }

    // epilogue: D lane mapping col=lane&15, row=(lane>>4)*4+r
#pragma unroll
    for (int m = 0; m < 4; ++m) {
#pragma unroll
        for (int n = 0; n < 4; ++n) {
            const int col = bn + wn * 64 + n * 16 + lr;
            if (col < Nlim) {
                const float bv = bias ? bias[col] : 0.f;
#pragma unroll
                for (int r = 0; r < 4; ++r) {
                    const int row = bm + wm * 64 + m * 16 + (lane >> 4) * 4 + r;
                    float v = acc[m][n][r] + bv;
                    if (ACT == 1) v = (v > 20.f) ? v : log1pf(__expf(v));
                    if constexpr (sizeof(CT) == 2)
                        C[(size_t)row * ldc + col] = f2b(v);
                    else
                        C[(size_t)row * ldc + col] = v;
                }
            }
        }
    }
}

// ---------------------------------------------------------------------------
// Transpose+convert: W[K,N] f32 -> Wt[Np,K] bf16 (rows n>=N zeroed).
// ---------------------------------------------------------------------------
__global__ __launch_bounds__(256) void transpose_cvt(
    const float* __restrict__ W, ushort* __restrict__ Wt,
    int K, int N, int Np)
{
    __shared__ float tile[32][33];
    const int t = threadIdx.x;
    const int tx = t & 31, ty = t >> 5;
    const int n0 = blockIdx.x * 32, k0 = blockIdx.y * 32;
#pragma unroll
    for (int i = 0; i < 4; ++i) {
        const int k = k0 + ty + i * 8;
        float v = 0.f;
        if (k < K && n0 + tx < N) v = W[(size_t)k * N + n0 + tx];
        tile[ty + i * 8][tx] = v;
    }
    __syncthreads();
#pragma unroll
    for (int i = 0; i < 4; ++i) {
        const int n = n0 + ty + i * 8;
        const int k = k0 + tx;
        if (n < Np && k < K) {
            const float v = (n < N) ? tile[tx][ty + i * 8] : 0.f;
            Wt[(size_t)n * K + k] = f2b(v);
        }
    }
}

// ---------------------------------------------------------------------------
__global__ __launch_bounds__(256) void cvt_f32_bf16(
    const float* __restrict__ in, ushort* __restrict__ out, int n4)
{
    const int idx = blockIdx.x * 256 + threadIdx.x;
    if (idx >= n4) return;
    const float4 v = reinterpret_cast<const float4*>(in)[idx];
    ushort4 o;
    o.x = f2b(v.x); o.y = f2b(v.y); o.z = f2b(v.z); o.w = f2b(v.w);
    reinterpret_cast<ushort4*>(out)[idx] = o;
}

// xdbl[:, 0:64] f32 -> dtA bf16 [8192,64]
__global__ __launch_bounds__(256) void cvt_dtA(
    const float* __restrict__ xdbl, ushort* __restrict__ dtA)
{
    const int idx = blockIdx.x * 256 + threadIdx.x;   // 131072
    const int row = idx >> 4, c4 = (idx & 15) * 4;
    const float4 v = *reinterpret_cast<const float4*>(xdbl + (size_t)row * 96 + c4);
    ushort4 o;
    o.x = f2b(v.x); o.y = f2b(v.y); o.z = f2b(v.z); o.w = f2b(v.w);
    *reinterpret_cast<ushort4*>(dtA + (size_t)row * 64 + c4) = o;
}

// ---------------------------------------------------------------------------
// Attention on bf16 full. One thread per q-row; online softmax; window skip.
// Scores s = q.k/8 - circ_dist; skipped keys (dist>128) have s < kept max by
// >120 -> exp underflows to 0 in f32; skip is exact.
// ---------------------------------------------------------------------------
__global__ __launch_bounds__(256) void attn_kernel(
    const ushort* __restrict__ full, const int* __restrict__ mask,
    float* __restrict__ out)
{
    __shared__ float Ks[64][64];
    __shared__ float Vs[64][64];
    __shared__ float Msk[64];

    const int t = threadIdx.x;
    const int bid = blockIdx.x;
    const int qt = bid & 3;
    const int bh = bid >> 2;
    const int h = bh & 15;
    const int b = bh >> 4;
    const int qrow = qt * 256 + t;
    const int q0 = qt * 256;

    const ushort* qp = full + ((size_t)(b * 1024 + qrow)) * 4096 + h * 64;
    float q[64];
#pragma unroll
    for (int c = 0; c < 8; ++c) {
        const uint4 u = *reinterpret_cast<const uint4*>(qp + c * 8);
        unpack2(u.x, q[c * 8 + 0], q[c * 8 + 1]);
        unpack2(u.y, q[c * 8 + 2], q[c * 8 + 3]);
        unpack2(u.z, q[c * 8 + 4], q[c * 8 + 5]);
        unpack2(u.w, q[c * 8 + 6], q[c * 8 + 7]);
    }

    float acc[64];
#pragma unroll
    for (int d = 0; d < 64; ++d) acc[d] = 0.f;
    float m = 0.f;     // diag score >= 0 is always kept
    float lsum = 0.f;

    for (int kt = 0; kt < 16; ++kt) {
        const int t0 = kt * 64;
        // block-level engage: interval distance([q0,q0+255],[t0,t0+63]) <= 128
        const int ovl1 = (q0 - t0) & 1023;
        const int ovl2 = (t0 - q0) & 1023;
        bool blk_engage = (ovl1 <= 63) || (ovl2 <= 255);
        if (!blk_engage) {
            const int f1 = (q0 - (t0 + 63)) & 1023;
            const int f2 = (t0 - (q0 + 255)) & 1023;
            blk_engage = (f1 < f2 ? f1 : f2) <= 128;
        }
        if (!blk_engage) continue;

        __syncthreads();
        {
            const int r = t >> 2;
            const int c0 = (t & 3) * 16;
            const ushort* kp = full + ((size_t)(b * 1024 + t0 + r)) * 4096 + 1024 + h * 64 + c0;
            const ushort* vp = kp + 1024;
#pragma unroll
            for (int half = 0; half < 2; ++half) {
                const uint4 ku = *reinterpret_cast<const uint4*>(kp + half * 8);
                const uint4 vu = *reinterpret_cast<const uint4*>(vp + half * 8);
                float* kd = &Ks[r][c0 + half * 8];
                float* vd = &Vs[r][c0 + half * 8];
                unpack2(ku.x, kd[0], kd[1]); unpack2(ku.y, kd[2], kd[3]);
                unpack2(ku.z, kd[4], kd[5]); unpack2(ku.w, kd[6], kd[7]);
                unpack2(vu.x, vd[0], vd[1]); unpack2(vu.y, vd[2], vd[3]);
                unpack2(vu.z, vd[4], vd[5]); unpack2(vu.w, vd[6], vd[7]);
            }
            if (t < 64) Msk[t] = (float)mask[b * 1024 + t0 + t];
        }
        __syncthreads();

        // per-thread engage (window 128 around qrow, circular)
        const int rel = (qrow - t0) & 1023;
        if (rel <= 191 || rel >= 896) {
            for (int j = 0; j < 64; ++j) {
                float s = 0.f;
                const float4* kr = reinterpret_cast<const float4*>(&Ks[j][0]);
#pragma unroll
                for (int d4 = 0; d4 < 16; ++d4) {
                    const float4 kv = kr[d4];
                    s += q[d4 * 4 + 0] * kv.x + q[d4 * 4 + 1] * kv.y +
                         q[d4 * 4 + 2] * kv.z + q[d4 * 4 + 3] * kv.w;
                }
                s *= 0.125f;
                const int ka = t0 + j;
                int dd = qrow - ka; if (dd < 0) dd = -dd;
                if (1024 - dd < dd) dd = 1024 - dd;
                s -= (float)dd;
                if (Msk[j] == 0.f) s = -1e9f;

                if (s > m) {
                    const float c = __expf(m - s);
                    lsum *= c;
#pragma unroll
                    for (int d = 0; d < 64; ++d) acc[d] *= c;
                    m = s;
                }
                const float p = __expf(s - m);
                lsum += p;
                if (p > 1e-12f) {
                    const float4* vr = reinterpret_cast<const float4*>(&Vs[j][0]);
#pragma unroll
                    for (int d4 = 0; d4 < 16; ++d4) {
                        const float4 vv = vr[d4];
                        acc[d4 * 4 + 0] += p * vv.x;
                        acc[d4 * 4 + 1] += p * vv.y;
                        acc[d4 * 4 + 2] += p * vv.z;
                        acc[d4 * 4 + 3] += p * vv.w;
                    }
                }
            }
        }
    }

    const float inv = 1.f / lsum;
    float* op = out + ((size_t)(b * 1024 + qrow)) * 1024 + h * 64;
#pragma unroll
    for (int d = 0; d < 64; d += 4) {
        float4 o4;
        o4.x = acc[d] * inv; o4.y = acc[d + 1] * inv;
        o4.z = acc[d + 2] * inv; o4.w = acc[d + 3] * inv;
        *reinterpret_cast<float4*>(op + d) = o4;
    }
}

// ---------------------------------------------------------------------------
__global__ __launch_bounds__(256) void rmsnorm_kernel(
    const float* __restrict__ in, const float* __restrict__ w,
    float* __restrict__ out)
{
    const int row = blockIdx.x;
    const int t = threadIdx.x;
    const float* x = in + (size_t)row * 1024;
    const float4 v = *reinterpret_cast<const float4*>(x + t * 4);
    float ss = v.x * v.x + v.y * v.y + v.z * v.z + v.w * v.w;
#pragma unroll
    for (int o = 32; o; o >>= 1) ss += __shfl_down(ss, o, 64);
    __shared__ float wsum[4];
    if ((t & 63) == 0) wsum[t >> 6] = ss;
    __syncthreads();
    const float tot = wsum[0] + wsum[1] + wsum[2] + wsum[3];
    const float scale = rsqrtf(tot * (1.f / 1024.f) + 1e-6f);
    const float4 wv = *reinterpret_cast<const float4*>(w + t * 4);
    float4 o4;
    o4.x = v.x * scale * wv.x; o4.y = v.y * scale * wv.y;
    o4.z = v.z * scale * wv.z; o4.w = v.w * scale * wv.w;
    *reinterpret_cast<float4*>(out + (size_t)row * 1024 + t * 4) = o4;
}

// ---------------------------------------------------------------------------
// Circular depthwise conv K=7; base bf16 strided 4096; out f32 [B,L,1024].
// ---------------------------------------------------------------------------
__global__ __launch_bounds__(256) void circconv_kernel(
    const ushort* __restrict__ base, const float* __restrict__ cw,
    const float* __restrict__ cb, float* __restrict__ out)
{
    const int idx = blockIdx.x * 256 + threadIdx.x;
    const int d = (idx & 255) * 4;
    const int bl = idx >> 8;
    const int l = bl & 1023;
    const int b = bl >> 10;
    float4 acc = make_float4(cb[d], cb[d + 1], cb[d + 2], cb[d + 3]);
#pragma unroll
    for (int k = 0; k < 7; ++k) {
        const int ll = (l + k - 3 + 1024) & 1023;
        const ushort4 xu = *reinterpret_cast<const ushort4*>(
            base + ((size_t)(b * 1024 + ll)) * 4096 + d);
        acc.x += b2f(xu.x) * cw[(d + 0) * 7 + k];
        acc.y += b2f(xu.y) * cw[(d + 1) * 7 + k];
        acc.z += b2f(xu.z) * cw[(d + 2) * 7 + k];
        acc.w += b2f(xu.w) * cw[(d + 3) * 7 + k];
    }
    *reinterpret_cast<float4*>(out + (size_t)bl * 1024 + d) = acc;
}

// ---------------------------------------------------------------------------
// Mamba causal conv DC=4 + SiLU; u bf16 (cols 0..2047 of full, stride 4096);
// uc bf16 (cols 2048..4095).
// ---------------------------------------------------------------------------
__global__ __launch_bounds__(256) void mconv_kernel(
    const ushort* __restrict__ u, const float* __restrict__ w,
    const float* __restrict__ bconv, ushort* __restrict__ uc)
{
    const int idx = blockIdx.x * 256 + threadIdx.x;  // B*L*512
    const int d = (idx & 511) * 4;
    const int bl = idx >> 9;
    const int l = bl & 1023;
    float4 acc = make_float4(bconv[d], bconv[d + 1], bconv[d + 2], bconv[d + 3]);
#pragma unroll
    for (int k = 0; k < 4; ++k) {
        const int ll = l + k - 3;
        if (ll >= 0) {
            const ushort4 xu = *reinterpret_cast<const ushort4*>(
                u + ((size_t)(bl + ll - l)) * 4096 + d);
            acc.x += b2f(xu.x) * w[(d + 0) * 4 + k];
            acc.y += b2f(xu.y) * w[(d + 1) * 4 + k];
            acc.z += b2f(xu.z) * w[(d + 2) * 4 + k];
            acc.w += b2f(xu.w) * w[(d + 3) * 4 + k];
        }
    }
    acc.x = acc.x / (1.f + __expf(-acc.x));
    acc.y = acc.y / (1.f + __expf(-acc.y));
    acc.z = acc.z / (1.f + __expf(-acc.z));
    acc.w = acc.w / (1.f + __expf(-acc.w));
    ushort4 o;
    o.x = f2b(acc.x); o.y = f2b(acc.y); o.z = f2b(acc.z); o.w = f2b(acc.w);
    *reinterpret_cast<ushort4*>(uc + (size_t)bl * 4096 + d) = o;
}

// ---------------------------------------------------------------------------
// Selective scan; dt & uc bf16 in full (cols 0..2047 / 2048..4095); z bf16;
// yg bf16 written in place over dt (wave-lockstep safe).
// ---------------------------------------------------------------------------
__global__ __launch_bounds__(256) void scan_kernel(
    ushort* __restrict__ dt_yg, const float* __restrict__ xdbl,
    const ushort* __restrict__ zb, const float* __restrict__ A_log,
    const float* __restrict__ Dp)
{
    const int g = blockIdx.x * 256 + threadIdx.x;
    const int s = g & 15;
    const int ch = g >> 4;
    const int di = ch & 2047;
    const int b = ch >> 11;

    const float A = -__expf(A_log[di * 16 + s]);
    const float Dv = Dp[di];
    float h = 0.f;
    const size_t base_di = (size_t)b * 1024 * 4096 + di;
    const size_t base_x = (size_t)b * 1024 * 96;
    const size_t base_z = (size_t)b * 1024 * 2048 + di;

    for (int t = 0; t < 1024; ++t) {
        const float dtv = b2f(dt_yg[base_di + (size_t)t * 4096]);
        const float uv = b2f(dt_yg[base_di + (size_t)t * 4096 + 2048]);
        const float Bv = xdbl[base_x + t * 96 + 64 + s];
        const float Cv = xdbl[base_x + t * 96 + 80 + s];
        const float e = __expf(dtv * A);
        h = e * h + dtv * uv * Bv;
        float y = h * Cv;
        y += __shfl_xor(y, 1, 64);
        y += __shfl_xor(y, 2, 64);
        y += __shfl_xor(y, 4, 64);
        y += __shfl_xor(y, 8, 64);
        if (s == 0) {
            const float zv = b2f(zb[base_z + (size_t)t * 2048]);
            const float yf = y + uv * Dv;
            const float sig = 1.f / (1.f + __expf(-zv));
            dt_yg[base_di + (size_t)t * 4096] = f2b(yf * zv * sig);
        }
    }
}

// ---------------------------------------------------------------------------
__global__ __launch_bounds__(256) void means_kernel(
    const float* __restrict__ a, const float* __restrict__ m,
    const float* __restrict__ c, float* __restrict__ ri)
{
    const int idx = blockIdx.x * 256 + threadIdx.x;  // 24576
    const int d = idx & 1023;
    const int br = (idx >> 10) % 3;
    const int b = idx / 3072;
    const float* src = (br == 0) ? a : ((br == 1) ? m : c);
    const float* p = src + (size_t)b * 1024 * 1024 + d;
    float sum = 0.f;
    for (int l = 0; l < 1024; ++l) sum += p[(size_t)l * 1024];
    ri[idx] = sum * (1.f / 1024.f);
}

// ---------------------------------------------------------------------------
__global__ __launch_bounds__(256) void router1_kernel(
    const float* __restrict__ ri, const float* __restrict__ w1,
    const float* __restrict__ b1, float* __restrict__ h1)
{
    __shared__ float rs[3072];
    const int b = blockIdx.y;
    const int jc = blockIdx.x;
    const int t = threadIdx.x;
    for (int i = t; i < 3072; i += 256) rs[i] = ri[b * 3072 + i];
    __syncthreads();
    const int j = jc * 256 + t;
    float acc = b1[j];
    for (int i = 0; i < 3072; ++i) acc += rs[i] * w1[(size_t)i * 1024 + j];
    h1[b * 1024 + j] = 0.5f * acc * (1.f + erff(acc * 0.70710678118654752f));
}

// ---------------------------------------------------------------------------
__global__ __launch_bounds__(256) void router2_kernel(
    const float* __restrict__ h1, const float* __restrict__ w2,
    const float* __restrict__ b2, float* __restrict__ gates)
{
    const int b = blockIdx.x;
    const int t = threadIdx.x;
    float p0 = 0.f, p1 = 0.f, p2 = 0.f;
    for (int j = t; j < 1024; j += 256) {
        const float hv = h1[b * 1024 + j];
        p0 += hv * w2[j * 3 + 0];
        p1 += hv * w2[j * 3 + 1];
        p2 += hv * w2[j * 3 + 2];
    }
#pragma unroll
    for (int o = 32; o; o >>= 1) {
        p0 += __shfl_down(p0, o, 64);
        p1 += __shfl_down(p1, o, 64);
        p2 += __shfl_down(p2, o, 64);
    }
    __shared__ float r0[4], r1[4], r2[4];
    if ((t & 63) == 0) { r0[t >> 6] = p0; r1[t >> 6] = p1; r2[t >> 6] = p2; }
    __syncthreads();
    if (t == 0) {
        float l0 = r0[0] + r0[1] + r0[2] + r0[3] + b2[0];
        float l1 = r1[0] + r1[1] + r1[2] + r1[3] + b2[1];
        float l2 = r2[0] + r2[1] + r2[2] + r2[3] + b2[2];
        const float mx = fmaxf(l0, fmaxf(l1, l2));
        const float e0 = __expf(l0 - mx), e1 = __expf(l1 - mx), e2 = __expf(l2 - mx);
        const float inv = 1.f / (e0 + e1 + e2);
        gates[b * 3 + 0] = e0 * inv;
        gates[b * 3 + 1] = e1 * inv;
        gates[b * 3 + 2] = e2 * inv;
    }
}

// ---------------------------------------------------------------------------
// fused = g0*a + g1*m + g2*c -> bf16
// ---------------------------------------------------------------------------
__global__ __launch_bounds__(256) void fuse_kernel(
    const float* __restrict__ a, const float* __restrict__ m,
    const float* __restrict__ c, const float* __restrict__ gates,
    ushort* __restrict__ fb)
{
    const int idx = blockIdx.x * 256 + threadIdx.x;
    const int b = idx >> 18;
    const float g0 = gates[b * 3 + 0];
    const float g1 = gates[b * 3 + 1];
    const float g2 = gates[b * 3 + 2];
    const float4 av = reinterpret_cast<const float4*>(a)[idx];
    const float4 mv = reinterpret_cast<const float4*>(m)[idx];
    const float4 cv = reinterpret_cast<const float4*>(c)[idx];
    ushort4 o;
    o.x = f2b(g0 * av.x + g1 * mv.x + g2 * cv.x);
    o.y = f2b(g0 * av.y + g1 * mv.y + g2 * cv.y);
    o.z = f2b(g0 * av.z + g1 * mv.z + g2 * cv.z);
    o.w = f2b(g0 * av.w + g1 * mv.w + g2 * cv.w);
    reinterpret_cast<ushort4*>(fb)[idx] = o;
}

// ---------------------------------------------------------------------------
extern "C" void kernel_launch(void* const* d_in, const int* in_sizes, int n_in,
                              void* d_out, int out_size, void* d_ws, size_t ws_size,
                              hipStream_t stream)
{
    const float* x        = (const float*)d_in[0];
    const int*   mask     = (const int*)d_in[1];
    const float* W_in     = (const float*)d_in[2];
    const float* b_in     = (const float*)d_in[3];
    const float* nw_attn  = (const float*)d_in[4];
    const float* nw_mamba = (const float*)d_in[5];
    const float* nw_cnn   = (const float*)d_in[6];
    const float* conv_w   = (const float*)d_in[7];
    const float* conv_b   = (const float*)d_in[8];
    const float* m_in_w   = (const float*)d_in[9];
    const float* m_conv_w = (const float*)d_in[10];
    const float* m_conv_b = (const float*)d_in[11];
    const float* m_x_w    = (const float*)d_in[12];
    const float* m_dt_w   = (const float*)d_in[13];
    const float* m_dt_b   = (const float*)d_in[14];
    const float* m_A_log  = (const float*)d_in[15];
    const float* m_D      = (const float*)d_in[16];
    const float* m_out_w  = (const float*)d_in[17];
    const float* r_w1     = (const float*)d_in[18];
    const float* r_b1     = (const float*)d_in[19];
    const float* r_w2     = (const float*)d_in[20];
    const float* r_b2     = (const float*)d_in[21];
    const float* W_out    = (const float*)d_in[22];
    const float* b_out    = (const float*)d_in[23];
    float* out = (float*)d_out;
    float* ws = (float*)d_ws;

    // Workspace (float-slot offsets), total ~155 MiB:
    ushort* full_bf = (ushort*)ws;                       // [8192,4096] bf16 (64 MiB)
    float*  zone1   = ws + 16777216ull;                  // 32 MiB multi-use
    ushort* xb      = (ushort*)zone1;                    // [8192,1024] bf16 (phase 1)
    ushort* z_bf    = (ushort*)zone1;                    // [8192,2048] bf16 (phase 2)
    float*  mamba_n = zone1;                             // [8192,1024] f32 (phase 3)
    float*  attn_n  = ws + 25165824ull;                  // [8192,1024] f32 (32 MiB)
    float*  xdbl    = ws + 33554432ull;                  // [8192,96] f32
    ushort* dtA     = (ushort*)(ws + 34340864ull);       // [8192,64] bf16
    ushort* Wt_in   = (ushort*)(ws + 34603008ull);       // [4096,1024]
    ushort* Wt_min  = (ushort*)(ws + 36700160ull);       // [4096,1024]
    ushort* Wt_x    = (ushort*)(ws + 38797312ull);       // [128,2048] (pad 96->128)
    ushort* Wt_dt   = (ushort*)(ws + 38928384ull);       // [2048,64]
    ushort* Wt_out  = (ushort*)(ws + 38993920ull);       // [1024,2048]
    ushort* Wt_fin  = (ushort*)(ws + 40042496ull);       // [1024,1024]
    float*  ri      = ws + 40566784ull;                  // [8,3072]
    float*  gates   = ri + 24576;
    float*  h1buf   = gates + 32;
    ushort* fusedb  = full_bf;                           // [8192,1024] bf16 (reuse)
    float*  cnn_n   = out;                               // [8192,1024] f32 in d_out

    const dim3 blk(256);

    // weight transposes + input cvt
    transpose_cvt<<<dim3(128, 32), blk, 0, stream>>>(W_in,   Wt_in, 1024, 4096, 4096);
    transpose_cvt<<<dim3(128, 32), blk, 0, stream>>>(m_in_w, Wt_min, 1024, 4096, 4096);
    transpose_cvt<<<dim3(4, 64),   blk, 0, stream>>>(m_x_w,  Wt_x, 2048, 96, 128);
    transpose_cvt<<<dim3(64, 2),   blk, 0, stream>>>(m_dt_w, Wt_dt, 64, 2048, 2048);
    transpose_cvt<<<dim3(32, 64),  blk, 0, stream>>>(m_out_w, Wt_out, 2048, 1024, 1024);
    transpose_cvt<<<dim3(32, 32),  blk, 0, stream>>>(W_out,  Wt_fin, 1024, 1024, 1024);
    cvt_f32_bf16<<<8192, blk, 0, stream>>>(x, xb, 2097152);

    // 1. full = x @ W_in + b_in (bf16 out)
    gemm_mfma<0, ushort><<<dim3(32, 64), blk, 0, stream>>>(
        xb, 1024, Wt_in, 1024, full_bf, 4096, 8192, 4096, 1024, 4096, b_in);
    // 2. attention branch
    attn_kernel<<<512, blk, 0, stream>>>(full_bf, mask, attn_n);
    rmsnorm_kernel<<<8192, blk, 0, stream>>>(attn_n, nw_attn, attn_n);
    // 3. cnn branch -> d_out
    circconv_kernel<<<8192, blk, 0, stream>>>(full_bf + 3072, conv_w, conv_b, cnn_n);
    rmsnorm_kernel<<<8192, blk, 0, stream>>>(cnn_n, nw_cnn, cnn_n);
    // 4. mamba in-proj: u -> full cols 0..2047 (bf16); z -> z_bf
    gemm_mfma<0, ushort><<<dim3(16, 64), blk, 0, stream>>>(
        full_bf + 3072, 4096, Wt_min, 1024, full_bf, 4096, 8192, 2048, 1024, 2048, nullptr);
    gemm_mfma<0, ushort><<<dim3(16, 64), blk, 0, stream>>>(
        full_bf + 3072, 4096, Wt_min + 2048ull * 1024, 1024, z_bf, 2048, 8192, 2048, 1024, 2048, nullptr);
    // 5. causal conv + silu: u -> uc (cols 2048..4095)
    mconv_kernel<<<16384, blk, 0, stream>>>(full_bf, m_conv_w, m_conv_b, full_bf + 2048);
    // 6. x_dbl = uc @ m_x_w (N pad 128, write 96)
    gemm_mfma<0, float><<<dim3(1, 64), blk, 0, stream>>>(
        full_bf + 2048, 4096, Wt_x, 2048, xdbl, 96, 8192, 128, 2048, 96, nullptr);
    cvt_dtA<<<512, blk, 0, stream>>>(xdbl, dtA);
    // 7. dt = softplus(dtA @ m_dt_w + m_dt_b) -> full cols 0..2047 (bf16)
    gemm_mfma<1, ushort><<<dim3(16, 64), blk, 0, stream>>>(
        dtA, 64, Wt_dt, 64, full_bf, 4096, 8192, 2048, 64, 2048, m_dt_b);
    // 8. scan -> yg bf16 in place over dt
    scan_kernel<<<1024, blk, 0, stream>>>(full_bf, xdbl, z_bf, m_A_log, m_D);
    // 9. mamba out-proj -> mamba_n (z dead)
    gemm_mfma<0, float><<<dim3(8, 64), blk, 0, stream>>>(
        full_bf, 4096, Wt_out, 2048, mamba_n, 1024, 8192, 1024, 2048, 1024, nullptr);
    rmsnorm_kernel<<<8192, blk, 0, stream>>>(mamba_n, nw_mamba, mamba_n);
    // 10. router
    means_kernel<<<96, blk, 0, stream>>>(attn_n, mamba_n, cnn_n, ri);
    router1_kernel<<<dim3(4, 8), blk, 0, stream>>>(ri, r_w1, r_b1, h1buf);
    router2_kernel<<<8, blk, 0, stream>>>(h1buf, r_w2, r_b2, gates);
    // 11. fuse -> fusedb bf16 (full_bf dead); final GEMM -> d_out
    fuse_kernel<<<8192, blk, 0, stream>>>(attn_n, mamba_n, cnn_n, gates, fusedb);
    gemm_mfma<0, float><<<dim3(8, 64), blk, 0, stream>>>(
        fusedb, 1024, Wt_fin, 1024, out, 1024, 8192, 1024, 1024, 1024, b_out);
}

// Round 4
// 1443.718 us; speedup vs baseline: 3.3918x; 1.3382x over previous
//
#include <hip/hip_runtime.h>
#include <math.h>

// B=8, L=1024, D=1024, H=16, HD=64, K=7, DI=2048, DS=16, DC=4, DTR=64

typedef __bf16 bf16x8 __attribute__((ext_vector_type(8)));
typedef float f32x4 __attribute__((ext_vector_type(4)));

__device__ __forceinline__ float b2f(ushort u) {
    return __uint_as_float(((unsigned int)u) << 16);
}
__device__ __forceinline__ ushort f2b(float f) {
    unsigned int x = __float_as_uint(f);
    return (ushort)((x + 0x7FFFu + ((x >> 16) & 1u)) >> 16);
}
__device__ __forceinline__ void unpack2(unsigned int u, float& a, float& b) {
    a = __uint_as_float(u << 16);
    b = __uint_as_float(u & 0xFFFF0000u);
}
__device__ __forceinline__ void async16(const ushort* g, ushort* l) {
    __builtin_amdgcn_global_load_lds(
        (const __attribute__((address_space(1))) unsigned int*)g,
        (__attribute__((address_space(3))) unsigned int*)l, 16, 0, 0);
}

// ---------------------------------------------------------------------------
// bf16 MFMA GEMM: C[M,N] = act(A[M,K] @ Bt[N,K]^T + bias[N])
// ---------------------------------------------------------------------------
template <int ACT, typename CT>
__global__ __launch_bounds__(256) void gemm_mfma(
    const ushort* __restrict__ A, int lda,
    const ushort* __restrict__ Bt, int ldb,
    CT* __restrict__ C, int ldc,
    int M, int N, int Kd, int Nlim,
    const float* __restrict__ bias)
{
    __shared__ ushort As[128 * 64];
    __shared__ ushort Bs[128 * 64];

    const int t = threadIdx.x;
    const int wid = t >> 6;
    const int lane = t & 63;
    const int bm = blockIdx.y * 128;
    const int bn = blockIdx.x * 128;
    const int wm = wid >> 1;
    const int wn = wid & 1;
    const int lr = lane & 15;
    const int lk = (lane >> 4) * 8;

    f32x4 acc[4][4];
#pragma unroll
    for (int m = 0; m < 4; ++m)
#pragma unroll
        for (int n = 0; n < 4; ++n) acc[m][n] = (f32x4){0.f, 0.f, 0.f, 0.f};

    for (int k0 = 0; k0 < Kd; k0 += 64) {
#pragma unroll
        for (int j = 0; j < 4; ++j) {
            const int r0 = wid * 32 + j * 8;
            const int grow = r0 + (lane >> 3);
            const int gcol = (lane & 7) * 8;
            async16(A + (size_t)(bm + grow) * lda + k0 + gcol, &As[r0 * 64]);
            async16(Bt + (size_t)(bn + grow) * ldb + k0 + gcol, &Bs[r0 * 64]);
        }
        __syncthreads();

#pragma unroll
        for (int kk = 0; kk < 64; kk += 32) {
            bf16x8 af[4], bq[4];
#pragma unroll
            for (int m = 0; m < 4; ++m)
                af[m] = *reinterpret_cast<const bf16x8*>(
                    &As[(wm * 64 + m * 16 + lr) * 64 + kk + lk]);
#pragma unroll
            for (int n = 0; n < 4; ++n)
                bq[n] = *reinterpret_cast<const bf16x8*>(
                    &Bs[(wn * 64 + n * 16 + lr) * 64 + kk + lk]);
#pragma unroll
            for (int m = 0; m < 4; ++m)
#pragma unroll
                for (int n = 0; n < 4; ++n)
                    acc[m][n] = __builtin_amdgcn_mfma_f32_16x16x32_bf16(
                        af[m], bq[n], acc[m][n], 0, 0, 0);
        }
        __syncthreads();
    }

#pragma unroll
    for (int m = 0; m < 4; ++m) {
#pragma unroll
        for (int n = 0; n < 4; ++n) {
            const int col = bn + wn * 64 + n * 16 + lr;
            if (col < Nlim) {
                const float bv = bias ? bias[col] : 0.f;
#pragma unroll
                for (int r = 0; r < 4; ++r) {
                    const int row = bm + wm * 64 + m * 16 + (lane >> 4) * 4 + r;
                    float v = acc[m][n][r] + bv;
                    if (ACT == 1) v = (v > 20.f) ? v : log1pf(__expf(v));
                    if constexpr (sizeof(CT) == 2)
                        C[(size_t)row * ldc + col] = f2b(v);
                    else
                        C[(size_t)row * ldc + col] = v;
                }
            }
        }
    }
}

// ---------------------------------------------------------------------------
__global__ __launch_bounds__(256) void transpose_cvt(
    const float* __restrict__ W, ushort* __restrict__ Wt,
    int K, int N, int Np)
{
    __shared__ float tile[32][33];
    const int t = threadIdx.x;
    const int tx = t & 31, ty = t >> 5;
    const int n0 = blockIdx.x * 32, k0 = blockIdx.y * 32;
#pragma unroll
    for (int i = 0; i < 4; ++i) {
        const int k = k0 + ty + i * 8;
        float v = 0.f;
        if (k < K && n0 + tx < N) v = W[(size_t)k * N + n0 + tx];
        tile[ty + i * 8][tx] = v;
    }
    __syncthreads();
#pragma unroll
    for (int i = 0; i < 4; ++i) {
        const int n = n0 + ty + i * 8;
        const int k = k0 + tx;
        if (n < Np && k < K) {
            const float v = (n < N) ? tile[tx][ty + i * 8] : 0.f;
            Wt[(size_t)n * K + k] = f2b(v);
        }
    }
}

// ---------------------------------------------------------------------------
__global__ __launch_bounds__(256) void cvt_f32_bf16(
    const float* __restrict__ in, ushort* __restrict__ out, int n4)
{
    const int idx = blockIdx.x * 256 + threadIdx.x;
    if (idx >= n4) return;
    const float4 v = reinterpret_cast<const float4*>(in)[idx];
    ushort4 o;
    o.x = f2b(v.x); o.y = f2b(v.y); o.z = f2b(v.z); o.w = f2b(v.w);
    reinterpret_cast<ushort4*>(out)[idx] = o;
}

// xdbl[:, 0:64] f32 -> dtA bf16 [8192,64]
__global__ __launch_bounds__(256) void cvt_dtA(
    const float* __restrict__ xdbl, ushort* __restrict__ dtA)
{
    const int idx = blockIdx.x * 256 + threadIdx.x;   // 131072
    const int row = idx >> 4, c4 = (idx & 15) * 4;
    const float4 v = *reinterpret_cast<const float4*>(xdbl + (size_t)row * 96 + c4);
    ushort4 o;
    o.x = f2b(v.x); o.y = f2b(v.y); o.z = f2b(v.z); o.w = f2b(v.w);
    *reinterpret_cast<ushort4*>(dtA + (size_t)row * 64 + c4) = o;
}

// ---------------------------------------------------------------------------
// Attention on bf16 full. One thread per q-row; online softmax; window skip.
// ---------------------------------------------------------------------------
__global__ __launch_bounds__(256) void attn_kernel(
    const ushort* __restrict__ full, const int* __restrict__ mask,
    float* __restrict__ out)
{
    __shared__ float Ks[64][64];
    __shared__ float Vs[64][64];
    __shared__ float Msk[64];

    const int t = threadIdx.x;
    const int bid = blockIdx.x;
    const int qt = bid & 3;
    const int bh = bid >> 2;
    const int h = bh & 15;
    const int b = bh >> 4;
    const int qrow = qt * 256 + t;
    const int q0 = qt * 256;

    const ushort* qp = full + ((size_t)(b * 1024 + qrow)) * 4096 + h * 64;
    float q[64];
#pragma unroll
    for (int c = 0; c < 8; ++c) {
        const uint4 u = *reinterpret_cast<const uint4*>(qp + c * 8);
        unpack2(u.x, q[c * 8 + 0], q[c * 8 + 1]);
        unpack2(u.y, q[c * 8 + 2], q[c * 8 + 3]);
        unpack2(u.z, q[c * 8 + 4], q[c * 8 + 5]);
        unpack2(u.w, q[c * 8 + 6], q[c * 8 + 7]);
    }

    float acc[64];
#pragma unroll
    for (int d = 0; d < 64; ++d) acc[d] = 0.f;
    float m = 0.f;
    float lsum = 0.f;

    for (int kt = 0; kt < 16; ++kt) {
        const int t0 = kt * 64;
        const int ovl1 = (q0 - t0) & 1023;
        const int ovl2 = (t0 - q0) & 1023;
        bool blk_engage = (ovl1 <= 63) || (ovl2 <= 255);
        if (!blk_engage) {
            const int f1 = (q0 - (t0 + 63)) & 1023;
            const int f2 = (t0 - (q0 + 255)) & 1023;
            blk_engage = (f1 < f2 ? f1 : f2) <= 128;
        }
        if (!blk_engage) continue;

        __syncthreads();
        {
            const int r = t >> 2;
            const int c0 = (t & 3) * 16;
            const ushort* kp = full + ((size_t)(b * 1024 + t0 + r)) * 4096 + 1024 + h * 64 + c0;
            const ushort* vp = kp + 1024;
#pragma unroll
            for (int half = 0; half < 2; ++half) {
                const uint4 ku = *reinterpret_cast<const uint4*>(kp + half * 8);
                const uint4 vu = *reinterpret_cast<const uint4*>(vp + half * 8);
                float* kd = &Ks[r][c0 + half * 8];
                float* vd = &Vs[r][c0 + half * 8];
                unpack2(ku.x, kd[0], kd[1]); unpack2(ku.y, kd[2], kd[3]);
                unpack2(ku.z, kd[4], kd[5]); unpack2(ku.w, kd[6], kd[7]);
                unpack2(vu.x, vd[0], vd[1]); unpack2(vu.y, vd[2], vd[3]);
                unpack2(vu.z, vd[4], vd[5]); unpack2(vu.w, vd[6], vd[7]);
            }
            if (t < 64) Msk[t] = (float)mask[b * 1024 + t0 + t];
        }
        __syncthreads();

        const int rel = (qrow - t0) & 1023;
        if (rel <= 191 || rel >= 896) {
            for (int j = 0; j < 64; ++j) {
                float s = 0.f;
                const float4* kr = reinterpret_cast<const float4*>(&Ks[j][0]);
#pragma unroll
                for (int d4 = 0; d4 < 16; ++d4) {
                    const float4 kv = kr[d4];
                    s += q[d4 * 4 + 0] * kv.x + q[d4 * 4 + 1] * kv.y +
                         q[d4 * 4 + 2] * kv.z + q[d4 * 4 + 3] * kv.w;
                }
                s *= 0.125f;
                const int ka = t0 + j;
                int dd = qrow - ka; if (dd < 0) dd = -dd;
                if (1024 - dd < dd) dd = 1024 - dd;
                s -= (float)dd;
                if (Msk[j] == 0.f) s = -1e9f;

                if (s > m) {
                    const float c = __expf(m - s);
                    lsum *= c;
#pragma unroll
                    for (int d = 0; d < 64; ++d) acc[d] *= c;
                    m = s;
                }
                const float p = __expf(s - m);
                lsum += p;
                if (p > 1e-12f) {
                    const float4* vr = reinterpret_cast<const float4*>(&Vs[j][0]);
#pragma unroll
                    for (int d4 = 0; d4 < 16; ++d4) {
                        const float4 vv = vr[d4];
                        acc[d4 * 4 + 0] += p * vv.x;
                        acc[d4 * 4 + 1] += p * vv.y;
                        acc[d4 * 4 + 2] += p * vv.z;
                        acc[d4 * 4 + 3] += p * vv.w;
                    }
                }
            }
        }
    }

    const float inv = 1.f / lsum;
    float* op = out + ((size_t)(b * 1024 + qrow)) * 1024 + h * 64;
#pragma unroll
    for (int d = 0; d < 64; d += 4) {
        float4 o4;
        o4.x = acc[d] * inv; o4.y = acc[d + 1] * inv;
        o4.z = acc[d + 2] * inv; o4.w = acc[d + 3] * inv;
        *reinterpret_cast<float4*>(op + d) = o4;
    }
}

// ---------------------------------------------------------------------------
__global__ __launch_bounds__(256) void rmsnorm_kernel(
    const float* __restrict__ in, const float* __restrict__ w,
    float* __restrict__ out)
{
    const int row = blockIdx.x;
    const int t = threadIdx.x;
    const float* x = in + (size_t)row * 1024;
    const float4 v = *reinterpret_cast<const float4*>(x + t * 4);
    float ss = v.x * v.x + v.y * v.y + v.z * v.z + v.w * v.w;
#pragma unroll
    for (int o = 32; o; o >>= 1) ss += __shfl_down(ss, o, 64);
    __shared__ float wsum[4];
    if ((t & 63) == 0) wsum[t >> 6] = ss;
    __syncthreads();
    const float tot = wsum[0] + wsum[1] + wsum[2] + wsum[3];
    const float scale = rsqrtf(tot * (1.f / 1024.f) + 1e-6f);
    const float4 wv = *reinterpret_cast<const float4*>(w + t * 4);
    float4 o4;
    o4.x = v.x * scale * wv.x; o4.y = v.y * scale * wv.y;
    o4.z = v.z * scale * wv.z; o4.w = v.w * scale * wv.w;
    *reinterpret_cast<float4*>(out + (size_t)row * 1024 + t * 4) = o4;
}

// ---------------------------------------------------------------------------
__global__ __launch_bounds__(256) void circconv_kernel(
    const ushort* __restrict__ base, const float* __restrict__ cw,
    const float* __restrict__ cb, float* __restrict__ out)
{
    const int idx = blockIdx.x * 256 + threadIdx.x;
    const int d = (idx & 255) * 4;
    const int bl = idx >> 8;
    const int l = bl & 1023;
    const int b = bl >> 10;
    float4 acc = make_float4(cb[d], cb[d + 1], cb[d + 2], cb[d + 3]);
#pragma unroll
    for (int k = 0; k < 7; ++k) {
        const int ll = (l + k - 3 + 1024) & 1023;
        const ushort4 xu = *reinterpret_cast<const ushort4*>(
            base + ((size_t)(b * 1024 + ll)) * 4096 + d);
        acc.x += b2f(xu.x) * cw[(d + 0) * 7 + k];
        acc.y += b2f(xu.y) * cw[(d + 1) * 7 + k];
        acc.z += b2f(xu.z) * cw[(d + 2) * 7 + k];
        acc.w += b2f(xu.w) * cw[(d + 3) * 7 + k];
    }
    *reinterpret_cast<float4*>(out + (size_t)bl * 1024 + d) = acc;
}

// ---------------------------------------------------------------------------
__global__ __launch_bounds__(256) void mconv_kernel(
    const ushort* __restrict__ u, const float* __restrict__ w,
    const float* __restrict__ bconv, ushort* __restrict__ uc)
{
    const int idx = blockIdx.x * 256 + threadIdx.x;
    const int d = (idx & 511) * 4;
    const int bl = idx >> 9;
    const int l = bl & 1023;
    float4 acc = make_float4(bconv[d], bconv[d + 1], bconv[d + 2], bconv[d + 3]);
#pragma unroll
    for (int k = 0; k < 4; ++k) {
        const int ll = l + k - 3;
        if (ll >= 0) {
            const ushort4 xu = *reinterpret_cast<const ushort4*>(
                u + ((size_t)(bl + ll - l)) * 4096 + d);
            acc.x += b2f(xu.x) * w[(d + 0) * 4 + k];
            acc.y += b2f(xu.y) * w[(d + 1) * 4 + k];
            acc.z += b2f(xu.z) * w[(d + 2) * 4 + k];
            acc.w += b2f(xu.w) * w[(d + 3) * 4 + k];
        }
    }
    acc.x = acc.x / (1.f + __expf(-acc.x));
    acc.y = acc.y / (1.f + __expf(-acc.y));
    acc.z = acc.z / (1.f + __expf(-acc.z));
    acc.w = acc.w / (1.f + __expf(-acc.w));
    ushort4 o;
    o.x = f2b(acc.x); o.y = f2b(acc.y); o.z = f2b(acc.z); o.w = f2b(acc.w);
    *reinterpret_cast<ushort4*>(uc + (size_t)bl * 4096 + d) = o;
}

// ---------------------------------------------------------------------------
// Selective scan, 4 states per thread (4 lanes per channel), 4-deep
// software pipeline. dt/uc bf16 in full (cols 0..2047 / 2048..4095); z bf16;
// yg bf16 written in place over dt (thread-owned slot, no hazard).
// grid: 256 blocks x 256 thr; lane = local_ch*4 + sg; sg handles s=sg*4..+3.
// ---------------------------------------------------------------------------
__global__ __launch_bounds__(256) void scan_kernel(
    ushort* __restrict__ dt_yg, const float* __restrict__ xdbl,
    const ushort* __restrict__ zb, const float* __restrict__ A_log,
    const float* __restrict__ Dp)
{
    const int t = threadIdx.x;
    const int sg = t & 3;
    const int chl = t >> 2;              // 0..63
    const int blk = blockIdx.x;          // 0..255
    const int b = blk >> 5;
    const int di = (blk & 31) * 64 + chl;

    float A0, A1, A2, A3;
    {
        const float4 av = *reinterpret_cast<const float4*>(&A_log[di * 16 + sg * 4]);
        A0 = -__expf(av.x); A1 = -__expf(av.y);
        A2 = -__expf(av.z); A3 = -__expf(av.w);
    }
    const float Dv = Dp[di];
    float h0 = 0.f, h1 = 0.f, h2 = 0.f, h3 = 0.f;

    const size_t rowbase = (size_t)b * 1024 * 4096 + di;
    const size_t zbase = (size_t)b * 1024 * 2048 + di;
    const size_t xbase = (size_t)b * 1024 * 96 + 64 + sg * 4;

    // 4 named prefetch sets, distance 4
    ushort dtu0, dtu1, dtu2, dtu3, ucu0, ucu1, ucu2, ucu3, zu0, zu1, zu2, zu3;
    float4 Bv0, Bv1, Bv2, Bv3, Cv0, Cv1, Cv2, Cv3;

#define LOADSET(i, tt)                                                          \
    dtu##i = dt_yg[rowbase + (size_t)(tt) * 4096];                              \
    ucu##i = dt_yg[rowbase + (size_t)(tt) * 4096 + 2048];                       \
    zu##i  = zb[zbase + (size_t)(tt) * 2048];                                   \
    Bv##i  = *reinterpret_cast<const float4*>(&xdbl[xbase + (size_t)(tt) * 96]);\
    Cv##i  = *reinterpret_cast<const float4*>(&xdbl[xbase + (size_t)(tt) * 96 + 16]);

    LOADSET(0, 0) LOADSET(1, 1) LOADSET(2, 2) LOADSET(3, 3)

#define STEP(i, tt)                                                             \
    {                                                                           \
        const float dtv = b2f(dtu##i);                                          \
        const float uv = b2f(ucu##i);                                           \
        const float zv = b2f(zu##i);                                            \
        const float4 Bc = Bv##i, Cc = Cv##i;                                    \
        const int nx = ((tt) + 4 < 1024) ? (tt) + 4 : 1023;                     \
        LOADSET(i, nx)                                                          \
        const float du = dtv * uv;                                              \
        h0 = __expf(dtv * A0) * h0 + du * Bc.x;                                 \
        h1 = __expf(dtv * A1) * h1 + du * Bc.y;                                 \
        h2 = __expf(dtv * A2) * h2 + du * Bc.z;                                 \
        h3 = __expf(dtv * A3) * h3 + du * Bc.w;                                 \
        float y = h0 * Cc.x + h1 * Cc.y + h2 * Cc.z + h3 * Cc.w;                \
        y += __shfl_xor(y, 1, 64);                                              \
        y += __shfl_xor(y, 2, 64);                                              \
        if (sg == 0) {                                                          \
            const float yf = y + uv * Dv;                                       \
            const float sig = 1.f / (1.f + __expf(-zv));                        \
            dt_yg[rowbase + (size_t)(tt) * 4096] = f2b(yf * zv * sig);          \
        }                                                                       \
    }

    for (int tt = 0; tt < 1024; tt += 4) {
        STEP(0, tt)
        STEP(1, tt + 1)
        STEP(2, tt + 2)
        STEP(3, tt + 3)
    }
#undef STEP
#undef LOADSET
}

// ---------------------------------------------------------------------------
__global__ __launch_bounds__(256) void means_kernel(
    const float* __restrict__ a, const float* __restrict__ m,
    const float* __restrict__ c, float* __restrict__ ri)
{
    const int idx = blockIdx.x * 256 + threadIdx.x;
    const int d = idx & 1023;
    const int br = (idx >> 10) % 3;
    const int b = idx / 3072;
    const float* src = (br == 0) ? a : ((br == 1) ? m : c);
    const float* p = src + (size_t)b * 1024 * 1024 + d;
    float sum = 0.f;
    for (int l = 0; l < 1024; ++l) sum += p[(size_t)l * 1024];
    ri[idx] = sum * (1.f / 1024.f);
}

// ---------------------------------------------------------------------------
__global__ __launch_bounds__(256) void router1_kernel(
    const float* __restrict__ ri, const float* __restrict__ w1,
    const float* __restrict__ b1, float* __restrict__ h1)
{
    __shared__ float rs[3072];
    const int b = blockIdx.y;
    const int jc = blockIdx.x;
    const int t = threadIdx.x;
    for (int i = t; i < 3072; i += 256) rs[i] = ri[b * 3072 + i];
    __syncthreads();
    const int j = jc * 256 + t;
    float acc = b1[j];
    for (int i = 0; i < 3072; ++i) acc += rs[i] * w1[(size_t)i * 1024 + j];
    h1[b * 1024 + j] = 0.5f * acc * (1.f + erff(acc * 0.70710678118654752f));
}

// ---------------------------------------------------------------------------
__global__ __launch_bounds__(256) void router2_kernel(
    const float* __restrict__ h1, const float* __restrict__ w2,
    const float* __restrict__ b2, float* __restrict__ gates)
{
    const int b = blockIdx.x;
    const int t = threadIdx.x;
    float p0 = 0.f, p1 = 0.f, p2 = 0.f;
    for (int j = t; j < 1024; j += 256) {
        const float hv = h1[b * 1024 + j];
        p0 += hv * w2[j * 3 + 0];
        p1 += hv * w2[j * 3 + 1];
        p2 += hv * w2[j * 3 + 2];
    }
#pragma unroll
    for (int o = 32; o; o >>= 1) {
        p0 += __shfl_down(p0, o, 64);
        p1 += __shfl_down(p1, o, 64);
        p2 += __shfl_down(p2, o, 64);
    }
    __shared__ float r0[4], r1[4], r2[4];
    if ((t & 63) == 0) { r0[t >> 6] = p0; r1[t >> 6] = p1; r2[t >> 6] = p2; }
    __syncthreads();
    if (t == 0) {
        float l0 = r0[0] + r0[1] + r0[2] + r0[3] + b2[0];
        float l1 = r1[0] + r1[1] + r1[2] + r1[3] + b2[1];
        float l2 = r2[0] + r2[1] + r2[2] + r2[3] + b2[2];
        const float mx = fmaxf(l0, fmaxf(l1, l2));
        const float e0 = __expf(l0 - mx), e1 = __expf(l1 - mx), e2 = __expf(l2 - mx);
        const float inv = 1.f / (e0 + e1 + e2);
        gates[b * 3 + 0] = e0 * inv;
        gates[b * 3 + 1] = e1 * inv;
        gates[b * 3 + 2] = e2 * inv;
    }
}

// ---------------------------------------------------------------------------
__global__ __launch_bounds__(256) void fuse_kernel(
    const float* __restrict__ a, const float* __restrict__ m,
    const float* __restrict__ c, const float* __restrict__ gates,
    ushort* __restrict__ fb)
{
    const int idx = blockIdx.x * 256 + threadIdx.x;
    const int b = idx >> 18;
    const float g0 = gates[b * 3 + 0];
    const float g1 = gates[b * 3 + 1];
    const float g2 = gates[b * 3 + 2];
    const float4 av = reinterpret_cast<const float4*>(a)[idx];
    const float4 mv = reinterpret_cast<const float4*>(m)[idx];
    const float4 cv = reinterpret_cast<const float4*>(c)[idx];
    ushort4 o;
    o.x = f2b(g0 * av.x + g1 * mv.x + g2 * cv.x);
    o.y = f2b(g0 * av.y + g1 * mv.y + g2 * cv.y);
    o.z = f2b(g0 * av.z + g1 * mv.z + g2 * cv.z);
    o.w = f2b(g0 * av.w + g1 * mv.w + g2 * cv.w);
    reinterpret_cast<ushort4*>(fb)[idx] = o;
}

// ---------------------------------------------------------------------------
extern "C" void kernel_launch(void* const* d_in, const int* in_sizes, int n_in,
                              void* d_out, int out_size, void* d_ws, size_t ws_size,
                              hipStream_t stream)
{
    const float* x        = (const float*)d_in[0];
    const int*   mask     = (const int*)d_in[1];
    const float* W_in     = (const float*)d_in[2];
    const float* b_in     = (const float*)d_in[3];
    const float* nw_attn  = (const float*)d_in[4];
    const float* nw_mamba = (const float*)d_in[5];
    const float* nw_cnn   = (const float*)d_in[6];
    const float* conv_w   = (const float*)d_in[7];
    const float* conv_b   = (const float*)d_in[8];
    const float* m_in_w   = (const float*)d_in[9];
    const float* m_conv_w = (const float*)d_in[10];
    const float* m_conv_b = (const float*)d_in[11];
    const float* m_x_w    = (const float*)d_in[12];
    const float* m_dt_w   = (const float*)d_in[13];
    const float* m_dt_b   = (const float*)d_in[14];
    const float* m_A_log  = (const float*)d_in[15];
    const float* m_D      = (const float*)d_in[16];
    const float* m_out_w  = (const float*)d_in[17];
    const float* r_w1     = (const float*)d_in[18];
    const float* r_b1     = (const float*)d_in[19];
    const float* r_w2     = (const float*)d_in[20];
    const float* r_b2     = (const float*)d_in[21];
    const float* W_out    = (const float*)d_in[22];
    const float* b_out    = (const float*)d_in[23];
    float* out = (float*)d_out;
    float* ws = (float*)d_ws;

    ushort* full_bf = (ushort*)ws;                       // [8192,4096] bf16
    float*  zone1   = ws + 16777216ull;
    ushort* xb      = (ushort*)zone1;                    // phase 1
    ushort* z_bf    = (ushort*)zone1;                    // phase 2
    float*  mamba_n = zone1;                             // phase 3
    float*  attn_n  = ws + 25165824ull;
    float*  xdbl    = ws + 33554432ull;
    ushort* dtA     = (ushort*)(ws + 34340864ull);
    ushort* Wt_in   = (ushort*)(ws + 34603008ull);
    ushort* Wt_min  = (ushort*)(ws + 36700160ull);
    ushort* Wt_x    = (ushort*)(ws + 38797312ull);
    ushort* Wt_dt   = (ushort*)(ws + 38928384ull);
    ushort* Wt_out  = (ushort*)(ws + 38993920ull);
    ushort* Wt_fin  = (ushort*)(ws + 40042496ull);
    float*  ri      = ws + 40566784ull;
    float*  gates   = ri + 24576;
    float*  h1buf   = gates + 32;
    ushort* fusedb  = full_bf;
    float*  cnn_n   = out;

    const dim3 blk(256);

    transpose_cvt<<<dim3(128, 32), blk, 0, stream>>>(W_in,   Wt_in, 1024, 4096, 4096);
    transpose_cvt<<<dim3(128, 32), blk, 0, stream>>>(m_in_w, Wt_min, 1024, 4096, 4096);
    transpose_cvt<<<dim3(4, 64),   blk, 0, stream>>>(m_x_w,  Wt_x, 2048, 96, 128);
    transpose_cvt<<<dim3(64, 2),   blk, 0, stream>>>(m_dt_w, Wt_dt, 64, 2048, 2048);
    transpose_cvt<<<dim3(32, 64),  blk, 0, stream>>>(m_out_w, Wt_out, 2048, 1024, 1024);
    transpose_cvt<<<dim3(32, 32),  blk, 0, stream>>>(W_out,  Wt_fin, 1024, 1024, 1024);
    cvt_f32_bf16<<<8192, blk, 0, stream>>>(x, xb, 2097152);

    gemm_mfma<0, ushort><<<dim3(32, 64), blk, 0, stream>>>(
        xb, 1024, Wt_in, 1024, full_bf, 4096, 8192, 4096, 1024, 4096, b_in);
    attn_kernel<<<512, blk, 0, stream>>>(full_bf, mask, attn_n);
    rmsnorm_kernel<<<8192, blk, 0, stream>>>(attn_n, nw_attn, attn_n);
    circconv_kernel<<<8192, blk, 0, stream>>>(full_bf + 3072, conv_w, conv_b, cnn_n);
    rmsnorm_kernel<<<8192, blk, 0, stream>>>(cnn_n, nw_cnn, cnn_n);
    gemm_mfma<0, ushort><<<dim3(16, 64), blk, 0, stream>>>(
        full_bf + 3072, 4096, Wt_min, 1024, full_bf, 4096, 8192, 2048, 1024, 2048, nullptr);
    gemm_mfma<0, ushort><<<dim3(16, 64), blk, 0, stream>>>(
        full_bf + 3072, 4096, Wt_min + 2048ull * 1024, 1024, z_bf, 2048, 8192, 2048, 1024, 2048, nullptr);
    mconv_kernel<<<16384, blk, 0, stream>>>(full_bf, m_conv_w, m_conv_b, full_bf + 2048);
    gemm_mfma<0, float><<<dim3(1, 64), blk, 0, stream>>>(
        full_bf + 2048, 4096, Wt_x, 2048, xdbl, 96, 8192, 128, 2048, 96, nullptr);
    cvt_dtA<<<512, blk, 0, stream>>>(xdbl, dtA);
    gemm_mfma<1, ushort><<<dim3(16, 64), blk, 0, stream>>>(
        dtA, 64, Wt_dt, 64, full_bf, 4096, 8192, 2048, 64, 2048, m_dt_b);
    scan_kernel<<<256, blk, 0, stream>>>(full_bf, xdbl, z_bf, m_A_log, m_D);
    gemm_mfma<0, float><<<dim3(8, 64), blk, 0, stream>>>(
        full_bf, 4096, Wt_out, 2048, mamba_n, 1024, 8192, 1024, 2048, 1024, nullptr);
    rmsnorm_kernel<<<8192, blk, 0, stream>>>(mamba_n, nw_mamba, mamba_n);
    means_kernel<<<96, blk, 0, stream>>>(attn_n, mamba_n, cnn_n, ri);
    router1_kernel<<<dim3(4, 8), blk, 0, stream>>>(ri, r_w1, r_b1, h1buf);
    router2_kernel<<<8, blk, 0, stream>>>(h1buf, r_w2, r_b2, gates);
    fuse_kernel<<<8192, blk, 0, stream>>>(attn_n, mamba_n, cnn_n, gates, fusedb);
    gemm_mfma<0, float><<<dim3(8, 64), blk, 0, stream>>>(
        fusedb, 1024, Wt_fin, 1024, out, 1024, 8192, 1024, 1024, 1024, b_out);
}

// Round 6
// 1162.048 us; speedup vs baseline: 4.2139x; 1.2424x over previous
//
#include <hip/hip_runtime.h>
#include <math.h>

// B=8, L=1024, D=1024, H=16, HD=64, K=7, DI=2048, DS=16, DC=4, DTR=64

typedef __bf16 bf16x8 __attribute__((ext_vector_type(8)));
typedef float f32x4 __attribute__((ext_vector_type(4)));

__device__ __forceinline__ float b2f(ushort u) {
    return __uint_as_float(((unsigned int)u) << 16);
}
__device__ __forceinline__ ushort f2b(float f) {
    unsigned int x = __float_as_uint(f);
    return (ushort)((x + 0x7FFFu + ((x >> 16) & 1u)) >> 16);
}
__device__ __forceinline__ void unpack2(unsigned int u, float& a, float& b) {
    a = __uint_as_float(u << 16);
    b = __uint_as_float(u & 0xFFFF0000u);
}
__device__ __forceinline__ void async16(const ushort* g, ushort* l) {
    __builtin_amdgcn_global_load_lds(
        (const __attribute__((address_space(1))) unsigned int*)g,
        (__attribute__((address_space(3))) unsigned int*)l, 16, 0, 0);
}

// ---------------------------------------------------------------------------
// bf16 MFMA GEMM: C[M,N] = act(A[M,K] @ Bt[N,K]^T + bias[N])
// ---------------------------------------------------------------------------
template <int ACT, typename CT>
__global__ __launch_bounds__(256) void gemm_mfma(
    const ushort* __restrict__ A, int lda,
    const ushort* __restrict__ Bt, int ldb,
    CT* __restrict__ C, int ldc,
    int M, int N, int Kd, int Nlim,
    const float* __restrict__ bias)
{
    __shared__ ushort As[128 * 64];
    __shared__ ushort Bs[128 * 64];

    const int t = threadIdx.x;
    const int wid = t >> 6;
    const int lane = t & 63;
    const int bm = blockIdx.y * 128;
    const int bn = blockIdx.x * 128;
    const int wm = wid >> 1;
    const int wn = wid & 1;
    const int lr = lane & 15;
    const int lk = (lane >> 4) * 8;

    f32x4 acc[4][4];
#pragma unroll
    for (int m = 0; m < 4; ++m)
#pragma unroll
        for (int n = 0; n < 4; ++n) acc[m][n] = (f32x4){0.f, 0.f, 0.f, 0.f};

    for (int k0 = 0; k0 < Kd; k0 += 64) {
#pragma unroll
        for (int j = 0; j < 4; ++j) {
            const int r0 = wid * 32 + j * 8;
            const int grow = r0 + (lane >> 3);
            const int gcol = (lane & 7) * 8;
            async16(A + (size_t)(bm + grow) * lda + k0 + gcol, &As[r0 * 64]);
            async16(Bt + (size_t)(bn + grow) * ldb + k0 + gcol, &Bs[r0 * 64]);
        }
        __syncthreads();

#pragma unroll
        for (int kk = 0; kk < 64; kk += 32) {
            bf16x8 af[4], bq[4];
#pragma unroll
            for (int m = 0; m < 4; ++m)
                af[m] = *reinterpret_cast<const bf16x8*>(
                    &As[(wm * 64 + m * 16 + lr) * 64 + kk + lk]);
#pragma unroll
            for (int n = 0; n < 4; ++n)
                bq[n] = *reinterpret_cast<const bf16x8*>(
                    &Bs[(wn * 64 + n * 16 + lr) * 64 + kk + lk]);
#pragma unroll
            for (int m = 0; m < 4; ++m)
#pragma unroll
                for (int n = 0; n < 4; ++n)
                    acc[m][n] = __builtin_amdgcn_mfma_f32_16x16x32_bf16(
                        af[m], bq[n], acc[m][n], 0, 0, 0);
        }
        __syncthreads();
    }

#pragma unroll
    for (int m = 0; m < 4; ++m) {
#pragma unroll
        for (int n = 0; n < 4; ++n) {
            const int col = bn + wn * 64 + n * 16 + lr;
            if (col < Nlim) {
                const float bv = bias ? bias[col] : 0.f;
#pragma unroll
                for (int r = 0; r < 4; ++r) {
                    const int row = bm + wm * 64 + m * 16 + (lane >> 4) * 4 + r;
                    float v = acc[m][n][r] + bv;
                    if (ACT == 1) v = (v > 20.f) ? v : log1pf(__expf(v));
                    if constexpr (sizeof(CT) == 2)
                        C[(size_t)row * ldc + col] = f2b(v);
                    else
                        C[(size_t)row * ldc + col] = v;
                }
            }
        }
    }
}

// ---------------------------------------------------------------------------
__global__ __launch_bounds__(256) void transpose_cvt(
    const float* __restrict__ W, ushort* __restrict__ Wt,
    int K, int N, int Np)
{
    __shared__ float tile[32][33];
    const int t = threadIdx.x;
    const int tx = t & 31, ty = t >> 5;
    const int n0 = blockIdx.x * 32, k0 = blockIdx.y * 32;
#pragma unroll
    for (int i = 0; i < 4; ++i) {
        const int k = k0 + ty + i * 8;
        float v = 0.f;
        if (k < K && n0 + tx < N) v = W[(size_t)k * N + n0 + tx];
        tile[ty + i * 8][tx] = v;
    }
    __syncthreads();
#pragma unroll
    for (int i = 0; i < 4; ++i) {
        const int n = n0 + ty + i * 8;
        const int k = k0 + tx;
        if (n < Np && k < K) {
            const float v = (n < N) ? tile[tx][ty + i * 8] : 0.f;
            Wt[(size_t)n * K + k] = f2b(v);
        }
    }
}

// ---------------------------------------------------------------------------
__global__ __launch_bounds__(256) void cvt_f32_bf16(
    const float* __restrict__ in, ushort* __restrict__ out, int n4)
{
    const int idx = blockIdx.x * 256 + threadIdx.x;
    if (idx >= n4) return;
    const float4 v = reinterpret_cast<const float4*>(in)[idx];
    ushort4 o;
    o.x = f2b(v.x); o.y = f2b(v.y); o.z = f2b(v.z); o.w = f2b(v.w);
    reinterpret_cast<ushort4*>(out)[idx] = o;
}

// xdbl[:, 0:64] f32 -> dtA bf16 [8192,64]
__global__ __launch_bounds__(256) void cvt_dtA(
    const float* __restrict__ xdbl, ushort* __restrict__ dtA)
{
    const int idx = blockIdx.x * 256 + threadIdx.x;   // 131072
    const int row = idx >> 4, c4 = (idx & 15) * 4;
    const float4 v = *reinterpret_cast<const float4*>(xdbl + (size_t)row * 96 + c4);
    ushort4 o;
    o.x = f2b(v.x); o.y = f2b(v.y); o.z = f2b(v.z); o.w = f2b(v.w);
    *reinterpret_cast<ushort4*>(dtA + (size_t)row * 64 + c4) = o;
}

// ---------------------------------------------------------------------------
// MFMA flash attention with circular window (exactly 5 engaged K-tiles).
// Block = (b, h, 64-row Q-tile), 4 waves; wave owns a 16-row strip.
// Q/K staged via global_load_lds w/ pre-swizzled source (elem ^= (row&7)<<3);
// V staged transposed w/ same swizzle; P via padded [16][72] per-wave LDS.
// D-layout: col = lane&15 (c), row = (lane>>4)*4 + r (g groups of 4 rows).
// ---------------------------------------------------------------------------
__global__ __launch_bounds__(256) void attn_mfma_kernel(
    const ushort* __restrict__ full, const int* __restrict__ mask,
    float* __restrict__ out)
{
    __shared__ ushort Qs[64 * 64];
    __shared__ ushort Ks[64 * 64];
    __shared__ ushort Vt[64 * 64];
    __shared__ ushort Ps[4][16 * 72];
    __shared__ float Msk[64];

    const int t = threadIdx.x;
    const int wid = t >> 6;
    const int lane = t & 63;
    const int c = lane & 15;
    const int g = lane >> 4;
    const int bid = blockIdx.x;
    const int qt = bid & 15;
    const int h = (bid >> 4) & 15;
    const int b = bid >> 8;
    const int q0 = qt * 64;

    // ---- stage Q (swizzled source) ----
#pragma unroll
    for (int s2 = wid; s2 < 8; s2 += 4) {
        const int grow = q0 + s2 * 8 + (lane >> 3);
        const int gcol = h * 64 + 8 * ((lane & 7) ^ (lane >> 3));
        async16(full + ((size_t)(b * 1024 + grow)) * 4096 + gcol, &Qs[s2 * 512]);
    }
    __syncthreads();

    bf16x8 qf0, qf1;
    {
        const int row = wid * 16 + c;
        const int sw = (row & 7) << 3;
        qf0 = *reinterpret_cast<const bf16x8*>(&Qs[row * 64 + ((g * 8) ^ sw)]);
        qf1 = *reinterpret_cast<const bf16x8*>(&Qs[row * 64 + ((32 + g * 8) ^ sw)]);
    }

    f32x4 o[4];
    float m[4], lsum[4];
#pragma unroll
    for (int n = 0; n < 4; ++n) o[n] = (f32x4){0.f, 0.f, 0.f, 0.f};
#pragma unroll
    for (int r = 0; r < 4; ++r) { m[r] = 0.f; lsum[r] = 0.f; }

    for (int dtile = 0; dtile < 5; ++dtile) {
        const int kt = (qt + dtile + 14) & 15;   // qt-2 .. qt+2 circular
        const int key0 = kt * 64;
        __syncthreads();
        // stage K (swizzled source)
#pragma unroll
        for (int s2 = wid; s2 < 8; s2 += 4) {
            const int grow = (key0 + s2 * 8 + (lane >> 3)) & 1023;
            const int gcol = 1024 + h * 64 + 8 * ((lane & 7) ^ (lane >> 3));
            async16(full + ((size_t)(b * 1024 + grow)) * 4096 + gcol, &Ks[s2 * 512]);
        }
        // stage V transposed (reg) with same swizzle
        {
            const int key = lane;
            const int grow = (key0 + key) & 1023;
            const ushort* vp = full + ((size_t)(b * 1024 + grow)) * 4096 + 2048 + h * 64 + wid * 16;
            const uint4 v0 = *reinterpret_cast<const uint4*>(vp);
            const uint4 v1 = *reinterpret_cast<const uint4*>(vp + 8);
            ushort vv[16];
            *reinterpret_cast<uint4*>(&vv[0]) = v0;
            *reinterpret_cast<uint4*>(&vv[8]) = v1;
#pragma unroll
            for (int i = 0; i < 16; ++i) {
                const int d = wid * 16 + i;
                Vt[d * 64 + (key ^ ((d & 7) << 3))] = vv[i];
            }
        }
        if (t < 64) Msk[t] = (float)mask[b * 1024 + ((key0 + t) & 1023)];
        __syncthreads();

        // S = Q @ K^T (16x64 per wave)
        f32x4 sa[4];
#pragma unroll
        for (int n = 0; n < 4; ++n) sa[n] = (f32x4){0.f, 0.f, 0.f, 0.f};
#pragma unroll
        for (int kk = 0; kk < 2; ++kk) {
            const bf16x8 qv = kk ? qf1 : qf0;
#pragma unroll
            for (int n = 0; n < 4; ++n) {
                const int row = n * 16 + c;
                const int colel = (kk * 32 + g * 8) ^ ((row & 7) << 3);
                const bf16x8 kf = *reinterpret_cast<const bf16x8*>(&Ks[row * 64 + colel]);
                sa[n] = __builtin_amdgcn_mfma_f32_16x16x32_bf16(qv, kf, sa[n], 0, 0, 0);
            }
        }

        // bias + mask + online softmax (rows live in (g, r); cols in (n, c))
        const int qgbase = q0 + wid * 16 + 4 * g;
        float p[4][4];
#pragma unroll
        for (int r = 0; r < 4; ++r) {
            float mx = -3.0e38f;
#pragma unroll
            for (int n = 0; n < 4; ++n) {
                const int key = (key0 + 16 * n + c) & 1023;
                int dd = qgbase + r - key; dd = (dd < 0) ? -dd : dd;
                dd = (1024 - dd < dd) ? 1024 - dd : dd;
                float s = sa[n][r] * 0.125f - (float)dd;
                if (Msk[16 * n + c] == 0.f) s = -1e9f;
                p[n][r] = s;
                mx = fmaxf(mx, s);
            }
            mx = fmaxf(mx, __shfl_xor(mx, 1, 64));
            mx = fmaxf(mx, __shfl_xor(mx, 2, 64));
            mx = fmaxf(mx, __shfl_xor(mx, 4, 64));
            mx = fmaxf(mx, __shfl_xor(mx, 8, 64));
            const float mnew = fmaxf(m[r], mx);
            const float corr = __expf(m[r] - mnew);
            m[r] = mnew;
            lsum[r] *= corr;
            o[0][r] *= corr; o[1][r] *= corr; o[2][r] *= corr; o[3][r] *= corr;
#pragma unroll
            for (int n = 0; n < 4; ++n) {
                const float pv = __expf(p[n][r] - mnew);
                p[n][r] = pv;
                lsum[r] += pv;    // per-lane partial; reduced in epilogue
            }
        }

        // write P (bf16) to per-wave LDS (stride 72 kills conflicts)
        ushort* pw = &Ps[wid][0];
#pragma unroll
        for (int r = 0; r < 4; ++r)
#pragma unroll
            for (int n = 0; n < 4; ++n)
                pw[(4 * g + r) * 72 + 16 * n + c] = f2b(p[n][r]);

        // O += P @ V  (per-wave DS ordering makes write->read safe)
#pragma unroll
        for (int kk = 0; kk < 2; ++kk) {
            const bf16x8 pf = *reinterpret_cast<const bf16x8*>(&pw[c * 72 + kk * 32 + g * 8]);
#pragma unroll
            for (int n = 0; n < 4; ++n) {
                const int d = 16 * n + c;
                const int colel = (kk * 32 + g * 8) ^ ((d & 7) << 3);
                const bf16x8 vf = *reinterpret_cast<const bf16x8*>(&Vt[d * 64 + colel]);
                o[n] = __builtin_amdgcn_mfma_f32_16x16x32_bf16(pf, vf, o[n], 0, 0, 0);
            }
        }
    }

    // epilogue: reduce lsum across the 16-lane col groups, normalize, store
#pragma unroll
    for (int r = 0; r < 4; ++r) {
        float ls = lsum[r];
        ls += __shfl_xor(ls, 1, 64);
        ls += __shfl_xor(ls, 2, 64);
        ls += __shfl_xor(ls, 4, 64);
        ls += __shfl_xor(ls, 8, 64);
        const float inv = 1.f / ls;
        const int qg = q0 + wid * 16 + 4 * g + r;
        float* op = out + ((size_t)(b * 1024 + qg)) * 1024 + h * 64 + c;
#pragma unroll
        for (int n = 0; n < 4; ++n)
            op[16 * n] = o[n][r] * inv;
    }
}

// ---------------------------------------------------------------------------
__global__ __launch_bounds__(256) void rmsnorm_kernel(
    const float* __restrict__ in, const float* __restrict__ w,
    float* __restrict__ out)
{
    const int row = blockIdx.x;
    const int t = threadIdx.x;
    const float* x = in + (size_t)row * 1024;
    const float4 v = *reinterpret_cast<const float4*>(x + t * 4);
    float ss = v.x * v.x + v.y * v.y + v.z * v.z + v.w * v.w;
#pragma unroll
    for (int o = 32; o; o >>= 1) ss += __shfl_down(ss, o, 64);
    __shared__ float wsum[4];
    if ((t & 63) == 0) wsum[t >> 6] = ss;
    __syncthreads();
    const float tot = wsum[0] + wsum[1] + wsum[2] + wsum[3];
    const float scale = rsqrtf(tot * (1.f / 1024.f) + 1e-6f);
    const float4 wv = *reinterpret_cast<const float4*>(w + t * 4);
    float4 o4;
    o4.x = v.x * scale * wv.x; o4.y = v.y * scale * wv.y;
    o4.z = v.z * scale * wv.z; o4.w = v.w * scale * wv.w;
    *reinterpret_cast<float4*>(out + (size_t)row * 1024 + t * 4) = o4;
}

// ---------------------------------------------------------------------------
__global__ __launch_bounds__(256) void circconv_kernel(
    const ushort* __restrict__ base, const float* __restrict__ cw,
    const float* __restrict__ cb, float* __restrict__ out)
{
    const int idx = blockIdx.x * 256 + threadIdx.x;
    const int d = (idx & 255) * 4;
    const int bl = idx >> 8;
    const int l = bl & 1023;
    const int b = bl >> 10;
    float4 acc = make_float4(cb[d], cb[d + 1], cb[d + 2], cb[d + 3]);
#pragma unroll
    for (int k = 0; k < 7; ++k) {
        const int ll = (l + k - 3 + 1024) & 1023;
        const ushort4 xu = *reinterpret_cast<const ushort4*>(
            base + ((size_t)(b * 1024 + ll)) * 4096 + d);
        acc.x += b2f(xu.x) * cw[(d + 0) * 7 + k];
        acc.y += b2f(xu.y) * cw[(d + 1) * 7 + k];
        acc.z += b2f(xu.z) * cw[(d + 2) * 7 + k];
        acc.w += b2f(xu.w) * cw[(d + 3) * 7 + k];
    }
    *reinterpret_cast<float4*>(out + (size_t)bl * 1024 + d) = acc;
}

// ---------------------------------------------------------------------------
__global__ __launch_bounds__(256) void mconv_kernel(
    const ushort* __restrict__ u, const float* __restrict__ w,
    const float* __restrict__ bconv, ushort* __restrict__ uc)
{
    const int idx = blockIdx.x * 256 + threadIdx.x;
    const int d = (idx & 511) * 4;
    const int bl = idx >> 9;
    const int l = bl & 1023;
    float4 acc = make_float4(bconv[d], bconv[d + 1], bconv[d + 2], bconv[d + 3]);
#pragma unroll
    for (int k = 0; k < 4; ++k) {
        const int ll = l + k - 3;
        if (ll >= 0) {
            const ushort4 xu = *reinterpret_cast<const ushort4*>(
                u + ((size_t)(bl + ll - l)) * 4096 + d);
            acc.x += b2f(xu.x) * w[(d + 0) * 4 + k];
            acc.y += b2f(xu.y) * w[(d + 1) * 4 + k];
            acc.z += b2f(xu.z) * w[(d + 2) * 4 + k];
            acc.w += b2f(xu.w) * w[(d + 3) * 4 + k];
        }
    }
    acc.x = acc.x / (1.f + __expf(-acc.x));
    acc.y = acc.y / (1.f + __expf(-acc.y));
    acc.z = acc.z / (1.f + __expf(-acc.z));
    acc.w = acc.w / (1.f + __expf(-acc.w));
    ushort4 o;
    o.x = f2b(acc.x); o.y = f2b(acc.y); o.z = f2b(acc.z); o.w = f2b(acc.w);
    *reinterpret_cast<ushort4*>(uc + (size_t)bl * 4096 + d) = o;
}

// ---------------------------------------------------------------------------
// Selective scan, 4 states per thread, 4-deep software pipeline.
// ---------------------------------------------------------------------------
__global__ __launch_bounds__(256) void scan_kernel(
    ushort* __restrict__ dt_yg, const float* __restrict__ xdbl,
    const ushort* __restrict__ zb, const float* __restrict__ A_log,
    const float* __restrict__ Dp)
{
    const int t = threadIdx.x;
    const int sg = t & 3;
    const int chl = t >> 2;
    const int blk = blockIdx.x;
    const int b = blk >> 5;
    const int di = (blk & 31) * 64 + chl;

    float A0, A1, A2, A3;
    {
        const float4 av = *reinterpret_cast<const float4*>(&A_log[di * 16 + sg * 4]);
        A0 = -__expf(av.x); A1 = -__expf(av.y);
        A2 = -__expf(av.z); A3 = -__expf(av.w);
    }
    const float Dv = Dp[di];
    float h0 = 0.f, h1 = 0.f, h2 = 0.f, h3 = 0.f;

    const size_t rowbase = (size_t)b * 1024 * 4096 + di;
    const size_t zbase = (size_t)b * 1024 * 2048 + di;
    const size_t xbase = (size_t)b * 1024 * 96 + 64 + sg * 4;

    ushort dtu0, dtu1, dtu2, dtu3, ucu0, ucu1, ucu2, ucu3, zu0, zu1, zu2, zu3;
    float4 Bv0, Bv1, Bv2, Bv3, Cv0, Cv1, Cv2, Cv3;

#define LOADSET(i, tt)                                                          \
    dtu##i = dt_yg[rowbase + (size_t)(tt) * 4096];                              \
    ucu##i = dt_yg[rowbase + (size_t)(tt) * 4096 + 2048];                       \
    zu##i  = zb[zbase + (size_t)(tt) * 2048];                                   \
    Bv##i  = *reinterpret_cast<const float4*>(&xdbl[xbase + (size_t)(tt) * 96]);\
    Cv##i  = *reinterpret_cast<const float4*>(&xdbl[xbase + (size_t)(tt) * 96 + 16]);

    LOADSET(0, 0) LOADSET(1, 1) LOADSET(2, 2) LOADSET(3, 3)

#define STEP(i, tt)                                                             \
    {                                                                           \
        const float dtv = b2f(dtu##i);                                          \
        const float uv = b2f(ucu##i);                                           \
        const float zv = b2f(zu##i);                                            \
        const float4 Bc = Bv##i, Cc = Cv##i;                                    \
        const int nx = ((tt) + 4 < 1024) ? (tt) + 4 : 1023;                     \
        LOADSET(i, nx)                                                          \
        const float du = dtv * uv;                                              \
        h0 = __expf(dtv * A0) * h0 + du * Bc.x;                                 \
        h1 = __expf(dtv * A1) * h1 + du * Bc.y;                                 \
        h2 = __expf(dtv * A2) * h2 + du * Bc.z;                                 \
        h3 = __expf(dtv * A3) * h3 + du * Bc.w;                                 \
        float y = h0 * Cc.x + h1 * Cc.y + h2 * Cc.z + h3 * Cc.w;                \
        y += __shfl_xor(y, 1, 64);                                              \
        y += __shfl_xor(y, 2, 64);                                              \
        if (sg == 0) {                                                          \
            const float yf = y + uv * Dv;                                       \
            const float sig = 1.f / (1.f + __expf(-zv));                        \
            dt_yg[rowbase + (size_t)(tt) * 4096] = f2b(yf * zv * sig);          \
        }                                                                       \
    }

    for (int tt = 0; tt < 1024; tt += 4) {
        STEP(0, tt)
        STEP(1, tt + 1)
        STEP(2, tt + 2)
        STEP(3, tt + 3)
    }
#undef STEP
#undef LOADSET
}

// ---------------------------------------------------------------------------
__global__ __launch_bounds__(256) void means_kernel(
    const float* __restrict__ a, const float* __restrict__ m,
    const float* __restrict__ c, float* __restrict__ ri)
{
    const int idx = blockIdx.x * 256 + threadIdx.x;
    const int d = idx & 1023;
    const int br = (idx >> 10) % 3;
    const int b = idx / 3072;
    const float* src = (br == 0) ? a : ((br == 1) ? m : c);
    const float* p = src + (size_t)b * 1024 * 1024 + d;
    float sum = 0.f;
    for (int l = 0; l < 1024; ++l) sum += p[(size_t)l * 1024];
    ri[idx] = sum * (1.f / 1024.f);
}

// ---------------------------------------------------------------------------
__global__ __launch_bounds__(256) void router1_kernel(
    const float* __restrict__ ri, const float* __restrict__ w1,
    const float* __restrict__ b1, float* __restrict__ h1)
{
    __shared__ float rs[3072];
    const int b = blockIdx.y;
    const int jc = blockIdx.x;
    const int t = threadIdx.x;
    for (int i = t; i < 3072; i += 256) rs[i] = ri[b * 3072 + i];
    __syncthreads();
    const int j = jc * 256 + t;
    float acc = b1[j];
    for (int i = 0; i < 3072; ++i) acc += rs[i] * w1[(size_t)i * 1024 + j];
    h1[b * 1024 + j] = 0.5f * acc * (1.f + erff(acc * 0.70710678118654752f));
}

// ---------------------------------------------------------------------------
__global__ __launch_bounds__(256) void router2_kernel(
    const float* __restrict__ h1, const float* __restrict__ w2,
    const float* __restrict__ b2, float* __restrict__ gates)
{
    const int b = blockIdx.x;
    const int t = threadIdx.x;
    float p0 = 0.f, p1 = 0.f, p2 = 0.f;
    for (int j = t; j < 1024; j += 256) {
        const float hv = h1[b * 1024 + j];
        p0 += hv * w2[j * 3 + 0];
        p1 += hv * w2[j * 3 + 1];
        p2 += hv * w2[j * 3 + 2];
    }
#pragma unroll
    for (int o = 32; o; o >>= 1) {
        p0 += __shfl_down(p0, o, 64);
        p1 += __shfl_down(p1, o, 64);
        p2 += __shfl_down(p2, o, 64);
    }
    __shared__ float r0[4], r1[4], r2[4];
    if ((t & 63) == 0) { r0[t >> 6] = p0; r1[t >> 6] = p1; r2[t >> 6] = p2; }
    __syncthreads();
    if (t == 0) {
        float l0 = r0[0] + r0[1] + r0[2] + r0[3] + b2[0];
        float l1 = r1[0] + r1[1] + r1[2] + r1[3] + b2[1];
        float l2 = r2[0] + r2[1] + r2[2] + r2[3] + b2[2];
        const float mx = fmaxf(l0, fmaxf(l1, l2));
        const float e0 = __expf(l0 - mx), e1 = __expf(l1 - mx), e2 = __expf(l2 - mx);
        const float inv = 1.f / (e0 + e1 + e2);
        gates[b * 3 + 0] = e0 * inv;
        gates[b * 3 + 1] = e1 * inv;
        gates[b * 3 + 2] = e2 * inv;
    }
}

// ---------------------------------------------------------------------------
__global__ __launch_bounds__(256) void fuse_kernel(
    const float* __restrict__ a, const float* __restrict__ m,
    const float* __restrict__ c, const float* __restrict__ gates,
    ushort* __restrict__ fb)
{
    const int idx = blockIdx.x * 256 + threadIdx.x;
    const int b = idx >> 18;
    const float g0 = gates[b * 3 + 0];
    const float g1 = gates[b * 3 + 1];
    const float g2 = gates[b * 3 + 2];
    const float4 av = reinterpret_cast<const float4*>(a)[idx];
    const float4 mv = reinterpret_cast<const float4*>(m)[idx];
    const float4 cv = reinterpret_cast<const float4*>(c)[idx];
    ushort4 o;
    o.x = f2b(g0 * av.x + g1 * mv.x + g2 * cv.x);
    o.y = f2b(g0 * av.y + g1 * mv.y + g2 * cv.y);
    o.z = f2b(g0 * av.z + g1 * mv.z + g2 * cv.z);
    o.w = f2b(g0 * av.w + g1 * mv.w + g2 * cv.w);
    reinterpret_cast<ushort4*>(fb)[idx] = o;
}

// ---------------------------------------------------------------------------
extern "C" void kernel_launch(void* const* d_in, const int* in_sizes, int n_in,
                              void* d_out, int out_size, void* d_ws, size_t ws_size,
                              hipStream_t stream)
{
    const float* x        = (const float*)d_in[0];
    const int*   mask     = (const int*)d_in[1];
    const float* W_in     = (const float*)d_in[2];
    const float* b_in     = (const float*)d_in[3];
    const float* nw_attn  = (const float*)d_in[4];
    const float* nw_mamba = (const float*)d_in[5];
    const float* nw_cnn   = (const float*)d_in[6];
    const float* conv_w   = (const float*)d_in[7];
    const float* conv_b   = (const float*)d_in[8];
    const float* m_in_w   = (const float*)d_in[9];
    const float* m_conv_w = (const float*)d_in[10];
    const float* m_conv_b = (const float*)d_in[11];
    const float* m_x_w    = (const float*)d_in[12];
    const float* m_dt_w   = (const float*)d_in[13];
    const float* m_dt_b   = (const float*)d_in[14];
    const float* m_A_log  = (const float*)d_in[15];
    const float* m_D      = (const float*)d_in[16];
    const float* m_out_w  = (const float*)d_in[17];
    const float* r_w1     = (const float*)d_in[18];
    const float* r_b1     = (const float*)d_in[19];
    const float* r_w2     = (const float*)d_in[20];
    const float* r_b2     = (const float*)d_in[21];
    const float* W_out    = (const float*)d_in[22];
    const float* b_out    = (const float*)d_in[23];
    float* out = (float*)d_out;
    float* ws = (float*)d_ws;

    ushort* full_bf = (ushort*)ws;                       // [8192,4096] bf16
    float*  zone1   = ws + 16777216ull;
    ushort* xb      = (ushort*)zone1;                    // phase 1
    ushort* z_bf    = (ushort*)zone1;                    // phase 2
    float*  mamba_n = zone1;                             // phase 3
    float*  attn_n  = ws + 25165824ull;
    float*  xdbl    = ws + 33554432ull;
    ushort* dtA     = (ushort*)(ws + 34340864ull);
    ushort* Wt_in   = (ushort*)(ws + 34603008ull);
    ushort* Wt_min  = (ushort*)(ws + 36700160ull);
    ushort* Wt_x    = (ushort*)(ws + 38797312ull);
    ushort* Wt_dt   = (ushort*)(ws + 38928384ull);
    ushort* Wt_out  = (ushort*)(ws + 38993920ull);
    ushort* Wt_fin  = (ushort*)(ws + 40042496ull);
    float*  ri      = ws + 40566784ull;
    float*  gates   = ri + 24576;
    float*  h1buf   = gates + 32;
    ushort* fusedb  = full_bf;
    float*  cnn_n   = out;

    const dim3 blk(256);

    transpose_cvt<<<dim3(128, 32), blk, 0, stream>>>(W_in,   Wt_in, 1024, 4096, 4096);
    transpose_cvt<<<dim3(128, 32), blk, 0, stream>>>(m_in_w, Wt_min, 1024, 4096, 4096);
    transpose_cvt<<<dim3(4, 64),   blk, 0, stream>>>(m_x_w,  Wt_x, 2048, 96, 128);
    transpose_cvt<<<dim3(64, 2),   blk, 0, stream>>>(m_dt_w, Wt_dt, 64, 2048, 2048);
    transpose_cvt<<<dim3(32, 64),  blk, 0, stream>>>(m_out_w, Wt_out, 2048, 1024, 1024);
    transpose_cvt<<<dim3(32, 32),  blk, 0, stream>>>(W_out,  Wt_fin, 1024, 1024, 1024);
    cvt_f32_bf16<<<8192, blk, 0, stream>>>(x, xb, 2097152);

    gemm_mfma<0, ushort><<<dim3(32, 64), blk, 0, stream>>>(
        xb, 1024, Wt_in, 1024, full_bf, 4096, 8192, 4096, 1024, 4096, b_in);
    attn_mfma_kernel<<<2048, blk, 0, stream>>>(full_bf, mask, attn_n);
    rmsnorm_kernel<<<8192, blk, 0, stream>>>(attn_n, nw_attn, attn_n);
    circconv_kernel<<<8192, blk, 0, stream>>>(full_bf + 3072, conv_w, conv_b, cnn_n);
    rmsnorm_kernel<<<8192, blk, 0, stream>>>(cnn_n, nw_cnn, cnn_n);
    gemm_mfma<0, ushort><<<dim3(16, 64), blk, 0, stream>>>(
        full_bf + 3072, 4096, Wt_min, 1024, full_bf, 4096, 8192, 2048, 1024, 2048, nullptr);
    gemm_mfma<0, ushort><<<dim3(16, 64), blk, 0, stream>>>(
        full_bf + 3072, 4096, Wt_min + 2048ull * 1024, 1024, z_bf, 2048, 8192, 2048, 1024, 2048, nullptr);
    mconv_kernel<<<16384, blk, 0, stream>>>(full_bf, m_conv_w, m_conv_b, full_bf + 2048);
    gemm_mfma<0, float><<<dim3(1, 64), blk, 0, stream>>>(
        full_bf + 2048, 4096, Wt_x, 2048, xdbl, 96, 8192, 128, 2048, 96, nullptr);
    cvt_dtA<<<512, blk, 0, stream>>>(xdbl, dtA);
    gemm_mfma<1, ushort><<<dim3(16, 64), blk, 0, stream>>>(
        dtA, 64, Wt_dt, 64, full_bf, 4096, 8192, 2048, 64, 2048, m_dt_b);
    scan_kernel<<<256, blk, 0, stream>>>(full_bf, xdbl, z_bf, m_A_log, m_D);
    gemm_mfma<0, float><<<dim3(8, 64), blk, 0, stream>>>(
        full_bf, 4096, Wt_out, 2048, mamba_n, 1024, 8192, 1024, 2048, 1024, nullptr);
    rmsnorm_kernel<<<8192, blk, 0, stream>>>(mamba_n, nw_mamba, mamba_n);
    means_kernel<<<96, blk, 0, stream>>>(attn_n, mamba_n, cnn_n, ri);
    router1_kernel<<<dim3(4, 8), blk, 0, stream>>>(ri, r_w1, r_b1, h1buf);
    router2_kernel<<<8, blk, 0, stream>>>(h1buf, r_w2, r_b2, gates);
    fuse_kernel<<<8192, blk, 0, stream>>>(attn_n, mamba_n, cnn_n, gates, fusedb);
    gemm_mfma<0, float><<<dim3(8, 64), blk, 0, stream>>>(
        fusedb, 1024, Wt_fin, 1024, out, 1024, 8192, 1024, 1024, 1024, b_out);
}